// Round 6
// baseline (267.804 us; speedup 1.0000x reference)
//
#include <hip/hip_runtime.h>
#include <cstdint>
#include <cstddef>

// Problem constants (B=128, S=256, H=128, HEADS=8, STEP=1)
#define BB   128
#define SS   256
#define HH   128
#define NH   8
#define DKK  16

typedef unsigned short u16;
typedef __attribute__((ext_vector_type(8))) short   sh8;    // 8 bf16 = 4 VGPRs (MFMA A/B frag)
typedef __attribute__((ext_vector_type(4))) float   f32x4;  // MFMA C/D frag

__device__ __forceinline__ float sigmoidf_(float x) { return 1.f / (1.f + expf(-x)); }

__device__ __forceinline__ u16 f2bf(float x) {
    union { float f; unsigned int u; } v; v.f = x;
    unsigned int r = (v.u + 0x7fffu + ((v.u >> 16) & 1u)) >> 16;  // RNE (finite inputs)
    return (u16)r;
}
__device__ __forceinline__ float bf2f(u16 u) {
    union { unsigned int u; float f; } v; v.u = ((unsigned int)u) << 16;
    return v.f;
}
// unpack lo/hi bf16 of a packed u32 (no addressable locals)
__device__ __forceinline__ float bflo(unsigned u) {
    union { unsigned u; float f; } v; v.u = u << 16; return v.f;
}
__device__ __forceinline__ float bfhi(unsigned u) {
    union { unsigned u; float f; } v; v.u = u & 0xffff0000u; return v.f;
}

// ===========================================================================
// GEMM: BK=32 single-buffer, 2 barriers/iter (round-0 known-good).
// Used for steps 2 and 5.  128x128 tile, 256 threads = 4 waves, wave 64x64
// (4x4 of 16x16x32).  B operands are B^T layout [N][K] bf16.
// XMODE 0 = bf16 [M][K] row-major (only mode used now)
// OMODE: 1 = bf16 row-major; 2 = bf16 TRANSPOSED (Out[col*ldo + row])
// ===========================================================================
#define BKk 32
#define PK  40   // LDS K pitch in halves (32 + 8): conflict-free frag reads

template<int XMODE, int OMODE>
__global__ __launch_bounds__(256) void gemm_mfma(
    const void* __restrict__ Xa, const void* __restrict__ Xc, int ldx, int ldx1, int ksplit,
    long long sXb, long long sXh,
    const u16* __restrict__ Bw, int ldb, long long sBb, long long sBh,
    const float* __restrict__ bias,
    void* __restrict__ Out, long long ldo, long long sOb, long long sOh,
    int K, const u16* __restrict__ hid)
{
    __shared__ __align__(16) char smem[2 * 128 * PK * 2];  // 20480 B
    u16* As = (u16*)smem;
    u16* Bs = (u16*)(smem + 128 * PK * 2);

    const int t  = threadIdx.x;
    const int bm = blockIdx.x * 128;
    const int bn = blockIdx.y * 128;
    const long long zb = blockIdx.z >> 1, zh = blockIdx.z & 1;

    const u16* Bp = Bw + zb * sBb + zh * sBh;

    const int wave = t >> 6, lane = t & 63;
    const int wr = (wave >> 1) * 64, wc = (wave & 1) * 64;
    const int fm = lane & 15, fq = lane >> 4;

    f32x4 acc[4][4] = {};

    const int r0  = t >> 2, kk0 = (t & 3) * 8;  // bf16 staging: 8 halves (16B), 2 chunks
    const int r1  = t >> 3, kk1 = (t & 7) * 4;  // fp32 staging: 4 floats, 4 chunks

    // prefetch registers — named scalars only (keep them out of scratch!)
    uint4  px0, px1, pb0, pb1;
    float4 pf0, pf1, pf2, pf3;

#define LOADX32(K0)                                                                  \
    if (XMODE == 1) {                                                                \
        const float* Xf_ = (const float*)Xa + zb * sXb + zh * sXh;                   \
        const float* xp_ = Xf_ + (long long)(bm + r1) * ldx + (K0) + kk1;            \
        pf0 = *(const float4*)(xp_);                                                 \
        pf1 = *(const float4*)(xp_ + 32LL * ldx);                                    \
        pf2 = *(const float4*)(xp_ + 64LL * ldx);                                    \
        pf3 = *(const float4*)(xp_ + 96LL * ldx);                                    \
    } else if (XMODE == 2 && (K0) >= ksplit) {                                       \
        const u16* xp_ = (const u16*)Xc + (long long)(bm + r0) * ldx1                \
                         + ((K0) - ksplit) + kk0;                                    \
        px0 = *(const uint4*)(xp_);                                                  \
        px1 = *(const uint4*)(xp_ + 64LL * ldx1);                                    \
    } else {                                                                         \
        const u16* xp_ = (const u16*)Xa + (long long)(bm + r0) * ldx + (K0) + kk0;   \
        px0 = *(const uint4*)(xp_);                                                  \
        px1 = *(const uint4*)(xp_ + 64LL * ldx);                                     \
    }

#define LOADB32(K0)                                                                  \
    {                                                                                \
        const u16* bp_ = Bp + (long long)(bn + r0) * ldb + (K0) + kk0;               \
        pb0 = *(const uint4*)(bp_);                                                  \
        pb1 = *(const uint4*)(bp_ + 64LL * ldb);                                     \
    }

    LOADX32(0)
    LOADB32(0)

    for (int k0 = 0; k0 < K; k0 += BKk) {
        // ---- commit prefetched tile to LDS ----
        if (XMODE == 1) {
            ushort4 w0 = { f2bf(pf0.x), f2bf(pf0.y), f2bf(pf0.z), f2bf(pf0.w) };
            ushort4 w1 = { f2bf(pf1.x), f2bf(pf1.y), f2bf(pf1.z), f2bf(pf1.w) };
            ushort4 w2 = { f2bf(pf2.x), f2bf(pf2.y), f2bf(pf2.z), f2bf(pf2.w) };
            ushort4 w3 = { f2bf(pf3.x), f2bf(pf3.y), f2bf(pf3.z), f2bf(pf3.w) };
            *(ushort4*)&As[(r1     ) * PK + kk1] = w0;
            *(ushort4*)&As[(r1 + 32) * PK + kk1] = w1;
            *(ushort4*)&As[(r1 + 64) * PK + kk1] = w2;
            *(ushort4*)&As[(r1 + 96) * PK + kk1] = w3;
        } else {
            *(uint4*)&As[(r0     ) * PK + kk0] = px0;
            *(uint4*)&As[(r0 + 64) * PK + kk0] = px1;
        }
        *(uint4*)&Bs[(r0     ) * PK + kk0] = pb0;
        *(uint4*)&Bs[(r0 + 64) * PK + kk0] = pb1;
        __syncthreads();

        // ---- issue next-tile loads (hide HBM latency behind frag+MFMA) ----
        if (k0 + BKk < K) {
            LOADX32(k0 + BKk)
            LOADB32(k0 + BKk)
        }

        sh8 af[4], bfr[4];
        #pragma unroll
        for (int i = 0; i < 4; i++) af[i]  = *(const sh8*)&As[(wr + i * 16 + fm) * PK + fq * 8];
        #pragma unroll
        for (int j = 0; j < 4; j++) bfr[j] = *(const sh8*)&Bs[(wc + j * 16 + fm) * PK + fq * 8];
        #pragma unroll
        for (int i = 0; i < 4; i++)
            #pragma unroll
            for (int j = 0; j < 4; j++)
                acc[i][j] = __builtin_amdgcn_mfma_f32_16x16x32_bf16(af[i], bfr[j], acc[i][j], 0, 0, 0);
        __syncthreads();
    }
#undef LOADX32
#undef LOADB32

    // ---- epilogue (round-0 original): C layout col=lane&15, row=(lane>>4)*4+reg ----
    #pragma unroll
    for (int j = 0; j < 4; j++) {
        const int col = bn + wc + j * 16 + fm;
        const float bj = bias ? bias[col] : 0.f;
        #pragma unroll
        for (int i = 0; i < 4; i++) {
            const int row0 = bm + wr + i * 16 + fq * 4;
            if (OMODE == 1) {
                u16* O = (u16*)Out + zb * sOb + zh * sOh;
                #pragma unroll
                for (int r = 0; r < 4; r++)
                    O[(long long)(row0 + r) * ldo + col] = f2bf(acc[i][j][r] + bj);
            } else {  // OMODE == 2
                u16* O = (u16*)Out + zb * sOb + zh * sOh;
                ushort4 w = { f2bf(acc[i][j][0] + bj), f2bf(acc[i][j][1] + bj),
                              f2bf(acc[i][j][2] + bj), f2bf(acc[i][j][3] + bj) };
                *(ushort4*)&O[(long long)col * ldo + row0] = w;  // 4 consecutive rows
            }
        }
    }
}

// ===========================================================================
// k_msg_gates v2: FUSED steps 3+4, 32 SESSION-ROWS per block (grid 1024).
// Round-5 post-mortem: 64-row version used 80.9 KB LDS -> <=2 blocks/CU,
// Occupancy 18.8%, MfmaUtil 9%, every pipe idle -> latency-bound on ~32
// serialized barrier phases with only 4 waves/CU-slot.  FETCH (78MB ~= A's
// 67MB) proved Et/W2 re-staging is L2/L3-absorbed, so redundancy is cheap;
// residency is the lever.  v2: Mloc[32][392]=25088B + staging 25600B =
// 50688 B LDS -> 3 blocks/CU (12 waves/CU), acc halves to [2][4].
//
// Phase 1: msg = A @ Et^T -> Mloc cols 0..255; h pre-staged in cols 256..383.
//          Waves 0/1: msg_in (A cols 0..255), waves 2/3: msg_out; wave w owns
//          ch 64w..64w+63; M=32 rows, K=256, 8 steps of 32 (2-barrier + reg
//          prefetch).
// Phase 2: gates = Mloc @ W2bf^T, K=384, two N-passes of 256 gate-ch
//          (pass p -> out-ch p*64..p*64+63; gates 4c+g interleaved), then the
//          verified GRU LDS-gather epilogue -> hnew bf16.
// ===========================================================================
#define MGP 392   // Mloc pitch (halves): b128-aligned, 2-way max conflict
#define SGP 40    // staging pitch (halves), same as PK

__global__ __launch_bounds__(256) void k_msg_gates(
    const float* __restrict__ A,       // [32768][512] fp32
    const u16*   __restrict__ Et,      // [256][32768] bf16 (E transposed)
    const u16*   __restrict__ h_bf,    // [32768][128] bf16
    const u16*   __restrict__ W2bf,    // [512][384] bf16, gate-interleaved rows
    const float* __restrict__ bias2,   // [512]
    u16*         __restrict__ hnew)    // [32768][128] bf16
{
    __shared__ __align__(16) char smem[50688];
    u16*   Mloc = (u16*)smem;               // [32][392]  (25088 B)
    u16*   As   = (u16*)(smem + 25088);     // [64][40]   (5120 B)  phase 1
    u16*   Bs   = (u16*)(smem + 30208);     // [256][40]  (20480 B) phase 1
    u16*   Ws   = (u16*)(smem + 25088);     // [256][40]  phase 2 (aliases As/Bs)
    float* Gs   = (float*)(smem + 25088);   // [16][260]  epilogue (aliases)

    const int t  = threadIdx.x;
    const int r0 = blockIdx.x * 32;         // global session-row base
    const int b  = blockIdx.x >> 3;         // batch (256 rows/batch, 32/block)

    const int wave = t >> 6, lane = t & 63;
    const int fm = lane & 15, fq = lane >> 4;
    const int zh = wave >> 1;               // phase-1 A half (0=in, 1=out)
    const int wn = wave * 64;               // wave N-base (ch / gate-ch local)

    const f32x4 fz = { 0.f, 0.f, 0.f, 0.f };
    f32x4 acc[2][4];

    // ---------------- stage h -> Mloc cols 256..383 (once) ----------------
    {
        const int hrow = t >> 3, cb = (t & 7) * 16;   // 32 rows x 128 halves
        const u16* hp = h_bf + (long long)(r0 + hrow) * HH + cb;
        uint4 h0 = *(const uint4*)(hp);
        uint4 h1 = *(const uint4*)(hp + 8);
        *(uint4*)&Mloc[hrow * MGP + 256 + cb    ] = h0;
        *(uint4*)&Mloc[hrow * MGP + 256 + cb + 8] = h1;
    }

    // ---------------- phase 1: msg -> Mloc cols 0..255 ----------------
    // A staging: 64 lds-rows (32 rows x 2 halves) x 32 cols; 4 threads/row.
    const int arow = t >> 2, acol = (t & 2) ? 8 : 0, acq = (t & 1) * 4;
    const int ac8 = (t & 3) * 8;            // 8 floats per thread
    const int arl = arow & 31, ah = arow >> 5;
    // Et staging: thread t = channel (0..127 E_in, 128..255 E_out)

    float4 qa0, qa1;
    uint4  qe0, qe1, qe2, qe3;

#define LOADP1(K0)                                                                   \
    {                                                                                \
        const float* ap_ = A + (long long)(r0 + arl) * 512 + ah * 256 + (K0) + ac8;  \
        qa0 = *(const float4*)(ap_);                                                 \
        qa1 = *(const float4*)(ap_ + 4);                                             \
        const u16* ep_ = Et + (long long)t * 32768 + b * 256 + (K0);                 \
        qe0 = *(const uint4*)(ep_);                                                  \
        qe1 = *(const uint4*)(ep_ + 8);                                              \
        qe2 = *(const uint4*)(ep_ + 16);                                             \
        qe3 = *(const uint4*)(ep_ + 24);                                             \
    }

#define COMMITP1                                                                     \
    {                                                                                \
        ushort4 a0 = { f2bf(qa0.x), f2bf(qa0.y), f2bf(qa0.z), f2bf(qa0.w) };         \
        ushort4 a1 = { f2bf(qa1.x), f2bf(qa1.y), f2bf(qa1.z), f2bf(qa1.w) };         \
        *(ushort4*)&As[arow * SGP + ac8    ] = a0;                                   \
        *(ushort4*)&As[arow * SGP + ac8 + 4] = a1;                                   \
        *(uint4*)&Bs[t * SGP     ] = qe0;                                            \
        *(uint4*)&Bs[t * SGP + 8 ] = qe1;                                            \
        *(uint4*)&Bs[t * SGP + 16] = qe2;                                            \
        *(uint4*)&Bs[t * SGP + 24] = qe3;                                            \
    }

    #pragma unroll
    for (int i = 0; i < 2; i++)
        #pragma unroll
        for (int j = 0; j < 4; j++) acc[i][j] = fz;

    LOADP1(0)
    for (int k0 = 0; k0 < 256; k0 += 32) {
        COMMITP1
        __syncthreads();
        if (k0 + 32 < 256) LOADP1(k0 + 32)
        sh8 af[2], bfr[4];
        #pragma unroll
        for (int i = 0; i < 2; i++)
            af[i]  = *(const sh8*)&As[(zh * 32 + i * 16 + fm) * SGP + fq * 8];
        #pragma unroll
        for (int j = 0; j < 4; j++)
            bfr[j] = *(const sh8*)&Bs[(wn + j * 16 + fm) * SGP + fq * 8];
        #pragma unroll
        for (int i = 0; i < 2; i++)
            #pragma unroll
            for (int j = 0; j < 4; j++)
                acc[i][j] = __builtin_amdgcn_mfma_f32_16x16x32_bf16(af[i], bfr[j], acc[i][j], 0, 0, 0);
        __syncthreads();
    }
#undef LOADP1
#undef COMMITP1

    // write msg (b_iah/b_oah folded into bias2 by prepw)
    // C layout: col=lane&15 -> ch, row=(lane>>4)*4+reg -> session row
    #pragma unroll
    for (int i = 0; i < 2; i++)
        #pragma unroll
        for (int j = 0; j < 4; j++)
            #pragma unroll
            for (int r = 0; r < 4; r++)
                Mloc[(i * 16 + fq * 4 + r) * MGP + wn + j * 16 + fm] = f2bf(acc[i][j][r]);
    __syncthreads();

    // ---------------- phase 2: gates + GRU, two N-passes ----------------
    uint4 qw0, qw1, qw2, qw3;

#define LOADP2(GB, K0)                                                               \
    {                                                                                \
        const u16* wp_ = W2bf + (long long)((GB) + t) * 384 + (K0);                  \
        qw0 = *(const uint4*)(wp_);                                                  \
        qw1 = *(const uint4*)(wp_ + 8);                                              \
        qw2 = *(const uint4*)(wp_ + 16);                                             \
        qw3 = *(const uint4*)(wp_ + 24);                                             \
    }

#define COMMITP2                                                                     \
    {                                                                                \
        *(uint4*)&Ws[t * SGP     ] = qw0;                                            \
        *(uint4*)&Ws[t * SGP + 8 ] = qw1;                                            \
        *(uint4*)&Ws[t * SGP + 16] = qw2;                                            \
        *(uint4*)&Ws[t * SGP + 24] = qw3;                                            \
    }

    for (int p = 0; p < 2; p++) {
        const int gb = p * 256;
        #pragma unroll
        for (int i = 0; i < 2; i++)
            #pragma unroll
            for (int j = 0; j < 4; j++) acc[i][j] = fz;

        LOADP2(gb, 0)
        for (int k0 = 0; k0 < 384; k0 += 32) {
            COMMITP2
            __syncthreads();
            if (k0 + 32 < 384) LOADP2(gb, k0 + 32)
            sh8 af[2], bfr[4];
            #pragma unroll
            for (int i = 0; i < 2; i++)
                af[i]  = *(const sh8*)&Mloc[(i * 16 + fm) * MGP + k0 + fq * 8];
            #pragma unroll
            for (int j = 0; j < 4; j++)
                bfr[j] = *(const sh8*)&Ws[(wn + j * 16 + fm) * SGP + fq * 8];
            #pragma unroll
            for (int i = 0; i < 2; i++)
                #pragma unroll
                for (int j = 0; j < 4; j++)
                    acc[i][j] = __builtin_amdgcn_mfma_f32_16x16x32_bf16(af[i], bfr[j], acc[i][j], 0, 0, 0);
            __syncthreads();
        }

        // GRU epilogue for out-ch [p*64, p*64+64): scatter 16-row chunks to
        // Gs fp32, gather 4 gates/channel, combine, store.
        const float bj0 = bias2[gb + wn + 0 * 16 + fm];
        const float bj1 = bias2[gb + wn + 1 * 16 + fm];
        const float bj2 = bias2[gb + wn + 2 * 16 + fm];
        const float bj3 = bias2[gb + wn + 3 * 16 + fm];
        #pragma unroll
        for (int i = 0; i < 2; i++) {
            #pragma unroll
            for (int r = 0; r < 4; r++) {
                Gs[(fq * 4 + r) * 260 + wn + 0 * 16 + fm] = acc[i][0][r] + bj0;
                Gs[(fq * 4 + r) * 260 + wn + 1 * 16 + fm] = acc[i][1][r] + bj1;
                Gs[(fq * 4 + r) * 260 + wn + 2 * 16 + fm] = acc[i][2][r] + bj2;
                Gs[(fq * 4 + r) * 260 + wn + 3 * 16 + fm] = acc[i][3][r] + bj3;
            }
            __syncthreads();
            {
                const int row_l = t >> 4, c0 = (t & 15) * 4;     // 4 out-ch/thread
                const long long grow = r0 + i * 16 + row_l;
                const ushort4 hv = *(const ushort4*)&h_bf[grow * HH + p * 64 + c0];
                const float hvv[4] = { bf2f(hv.x), bf2f(hv.y), bf2f(hv.z), bf2f(hv.w) };
                ushort4 w;
                u16* wp = (u16*)&w;
                #pragma unroll
                for (int m = 0; m < 4; m++) {
                    f32x4 gv = *(const f32x4*)&Gs[row_l * 260 + (t & 15) * 16 + 4 * m];
                    float rg = sigmoidf_(gv[0]);
                    float ig = sigmoidf_(gv[1]);
                    float ng = tanhf(gv[2] + rg * gv[3]);
                    wp[m] = f2bf(hvv[m] - ig * (hvv[m] - ng));
                }
                *(ushort4*)&hnew[grow * HH + p * 64 + c0] = w;
            }
            __syncthreads();
        }
    }
#undef LOADP2
#undef COMMITP2
}

// ---------------------------------------------------------------------------
// Weight prep + hidden cast (one kernel, grid 4096x256).
//   h_bf = bf16(hidden)  (1048576 float4s)
//   W2bf [512x384], GATE-INTERLEAVED rows: np = 4c+g, g: 0=r 1=i 2=n 3=hn.
//   bias2[np] = gate bias + fold of (b_iah|b_oah) through w_ih (linear terms).
//   Wcat [256x128] = [W_ein; W_eout], biascat = [b_ein|b_eout]
//   Wq12 [256x128] = [W_q1; W_q2],    biasq12 = [b_q1|b_q2]
// ---------------------------------------------------------------------------
__global__ __launch_bounds__(256) void k_prepw(
    const float* __restrict__ hidden, u16* __restrict__ h_bf,
    const float* __restrict__ w_ih, const float* __restrict__ w_hh,
    const float* __restrict__ b_ih, const float* __restrict__ b_hh,
    const float* __restrict__ b_iah, const float* __restrict__ b_oah,
    const float* __restrict__ W_ein, const float* __restrict__ b_ein,
    const float* __restrict__ W_eout, const float* __restrict__ b_eout,
    const float* __restrict__ W_q1, const float* __restrict__ b_q1,
    const float* __restrict__ W_q2, const float* __restrict__ b_q2,
    u16* __restrict__ W2bf, float* __restrict__ bias2,
    u16* __restrict__ Wcat, float* __restrict__ biascat,
    u16* __restrict__ Wq12, float* __restrict__ biasq12)
{
    int idx = blockIdx.x * 256 + threadIdx.x;  // 0 .. 1048575
    {   // hidden -> bf16, 4 elems/thread
        float4 v = ((const float4*)hidden)[idx];
        ushort4 w = { f2bf(v.x), f2bf(v.y), f2bf(v.z), f2bf(v.w) };
        ((ushort4*)h_bf)[idx] = w;
    }
    if (idx < 512 * 384) {
        int np = idx / 384, kk = idx % 384;
        int c = np >> 2, g = np & 3;
        float v;
        if (g < 2)       v = (kk < 256) ? w_ih[(g * 128 + c) * 256 + kk]
                                        : w_hh[(g * 128 + c) * 128 + kk - 256];
        else if (g == 2) v = (kk < 256) ? w_ih[(256 + c) * 256 + kk] : 0.f;
        else             v = (kk < 256) ? 0.f : w_hh[(256 + c) * 128 + kk - 256];
        W2bf[idx] = f2bf(v);
    }
    if (idx < 256 * 128) {
        int n = idx >> 7, k = idx & 127;
        Wcat[idx] = f2bf(n < 128 ? W_ein[n * 128 + k] : W_eout[(n - 128) * 128 + k]);
        Wq12[idx] = f2bf(n < 128 ? W_q1[n * 128 + k]  : W_q2[(n - 128) * 128 + k]);
    }
    if (idx < 512) {
        int np = idx, c = np >> 2, g = np & 3;
        float s;
        if (g < 2)       s = b_ih[g * 128 + c] + b_hh[g * 128 + c];
        else if (g == 2) s = b_ih[256 + c];
        else             s = b_hh[256 + c];
        if (g < 3) {
            int n = (g < 2) ? g * 128 + c : 256 + c;
            for (int k = 0; k < 128; k++)
                s += w_ih[n * 256 + k] * b_iah[k] + w_ih[n * 256 + 128 + k] * b_oah[k];
        }
        bias2[np] = s;
    }
    if (idx < 256) {
        biascat[idx] = idx < 128 ? b_ein[idx] : b_eout[idx - 128];
        biasq12[idx] = idx < 128 ? b_q1[idx]  : b_q2[idx - 128];
    }
}

// ---------------------------------------------------------------------------
// Fused attention tail v3: grid (B, 2) — 2 blocks per batch so all 256 CUs
// are covered.  Each block recomputes the cheap score/softmax phases and
// handles 64 of the 128 output columns in the readout (paired-column uint
// loads).  Mask sum via wave shfl-reduce.  q12 is bf16 [32768][256]
// (cols 0:128 = q1, 128:256 = q2).
// ---------------------------------------------------------------------------
__global__ __launch_bounds__(1024) void k_tail(
    const u16* __restrict__ hnew_bf, const int* __restrict__ mask,
    const u16* __restrict__ q12, const float* __restrict__ Wq0,
    const float* __restrict__ bq0, float* __restrict__ out)
{
    const int b = blockIdx.x, chb = blockIdx.y, t = threadIdx.x;
    __shared__ float red[1024];
    __shared__ float red2[1024][2];
    __shared__ float hs[HH];
    __shared__ float q0s[HH];
    __shared__ float p_s[NH][SS];
    __shared__ float w_s[NH][SS];
    __shared__ int s_nv;

    // ---- mask sum / last index: wave shfl-reduce ----
    if (t < 256) {
        int v = mask[b * SS + t];
        #pragma unroll
        for (int m = 1; m < 64; m <<= 1) v += __shfl_xor(v, m, 64);
        if ((t & 63) == 0) red[t >> 6] = (float)v;
    }
    __syncthreads();
    if (t == 0) s_nv = (int)(red[0] + red[1] + red[2] + red[3]);
    __syncthreads();
    const int nv = s_nv;
    const int last = (nv - 1) & (SS - 1);

    if (t < HH) hs[t] = bf2f(hnew_bf[((size_t)b * SS + last) * HH + t]);
    __syncthreads();

    // ---- q0 = h_last @ Wq0^T + bq0: n = t&127, K split 8 ways ----
    {
        const int n = t & 127, kh = t >> 7;  // kh 0..7, 16 k each
        const float* w = Wq0 + (size_t)n * HH + kh * 16;
        const float* h = hs + kh * 16;
        float s = 0.f;
        #pragma unroll
        for (int k = 0; k < 16; k++) s += h[k] * w[k];
        red[t] = s;
    }
    __syncthreads();
    if (t < HH) {
        float s = bq0[t];
        #pragma unroll
        for (int kh = 0; kh < 8; kh++) s += red[kh * 128 + t];
        q0s[t] = s;
    }
    __syncthreads();

    // ---- scores: j = t>>2 (256), q = t&3; thread computes heads 2q, 2q+1 ----
    {
        const int j = t >> 2, q = t & 3;
        const u16* q1r = q12 + ((size_t)b * SS + j) * 256 + q * 32;
        uint4 va = *(const uint4*)(q1r);
        uint4 vb = *(const uint4*)(q1r + 8);
        uint4 vc = *(const uint4*)(q1r + 16);
        uint4 vd = *(const uint4*)(q1r + 24);
        const float* qa = q0s + q * 32;
        float s0 = qa[0]  * bflo(va.x) + qa[1]  * bfhi(va.x)
                 + qa[2]  * bflo(va.y) + qa[3]  * bfhi(va.y)
                 + qa[4]  * bflo(va.z) + qa[5]  * bfhi(va.z)
                 + qa[6]  * bflo(va.w) + qa[7]  * bfhi(va.w)
                 + qa[8]  * bflo(vb.x) + qa[9]  * bfhi(vb.x)
                 + qa[10] * bflo(vb.y) + qa[11] * bfhi(vb.y)
                 + qa[12] * bflo(vb.z) + qa[13] * bfhi(vb.z)
                 + qa[14] * bflo(vb.w) + qa[15] * bfhi(vb.w);
        float s1 = qa[16] * bflo(vc.x) + qa[17] * bfhi(vc.x)
                 + qa[18] * bflo(vc.y) + qa[19] * bfhi(vc.y)
                 + qa[20] * bflo(vc.z) + qa[21] * bfhi(vc.z)
                 + qa[22] * bflo(vc.w) + qa[23] * bfhi(vc.w)
                 + qa[24] * bflo(vd.x) + qa[25] * bfhi(vd.x)
                 + qa[26] * bflo(vd.y) + qa[27] * bfhi(vd.y)
                 + qa[28] * bflo(vd.z) + qa[29] * bfhi(vd.z)
                 + qa[30] * bflo(vd.w) + qa[31] * bfhi(vd.w);
        p_s[2 * q][j]     = sigmoidf_(s0);
        p_s[2 * q + 1][j] = sigmoidf_(s1);
    }
    __syncthreads();

    // ---- softmax over j per head (threads 0..255: 32 lanes/head, 8 vals) ----
    if (t < 256) {
        const int h = t >> 5, l = t & 31;
        float v[8], m = -1e30f;
        #pragma unroll
        for (int u = 0; u < 8; u++) { v[u] = p_s[h][l * 8 + u]; m = fmaxf(m, v[u]); }
        #pragma unroll
        for (int msk = 1; msk < 32; msk <<= 1) m = fmaxf(m, __shfl_xor(m, msk, 32));
        float sum = 0.f;
        #pragma unroll
        for (int u = 0; u < 8; u++) { v[u] = expf(v[u] - m); sum += v[u]; }
        #pragma unroll
        for (int msk = 1; msk < 32; msk <<= 1) sum += __shfl_xor(sum, msk, 32);
        const float inv = 1.f / sum;
        #pragma unroll
        for (int u = 0; u < 8; u++) p_s[h][l * 8 + u] = v[u] * inv;
    }
    __syncthreads();

    // ---- head softmax per j (threads 0..255) ----
    if (t < 256) {
        float e[NH], den = 0.f;
        #pragma unroll
        for (int h = 0; h < NH; h++) { e[h] = expf(2.f * p_s[h][t]); den += e[h]; }
        const float inv = 1.f / den;
        #pragma unroll
        for (int h = 0; h < NH; h++) w_s[h][t] = e[h] * inv;
    }
    __syncthreads();

    // ---- readout: this block owns cols [chb*64, chb*64+64).
    //      col pair cp = t&31 (2 cols via one uint load), j split 32 ways ----
    {
        const int cp = t & 31, jq = t >> 5;
        const int col = chb * 64 + cp * 2;
        const int h0 = col >> 4;                    // col even -> both in same head
        const u16* q2b = q12 + (size_t)b * SS * 256 + 128 + col;
        float a0 = 0.f, a1 = 0.f;
        #pragma unroll
        for (int u = 0; u < 8; u++) {
            const int j = jq * 8 + u;
            const unsigned v = *(const unsigned*)&q2b[(size_t)j * 256];
            const float w = w_s[h0][j];
            a0 += w * bflo(v);
            a1 += w * bfhi(v);
        }
        red2[t][0] = a0;
        red2[t][1] = a1;
    }
    __syncthreads();
    // 32 col-pairs x 2 parities = 64 outputs for this block
    if (t < 64) {
        const int cp2 = t >> 1, par = t & 1;
        float s = 0.f;
        #pragma unroll
        for (int q = 0; q < 32; q++) s += red2[q * 32 + cp2][par];
        out[(size_t)b * HH + chb * 64 + cp2 * 2 + par] = s * (float)nv;
    }
}

// ---------------------------------------------------------------------------
extern "C" void kernel_launch(void* const* d_in, const int* in_sizes, int n_in,
                              void* d_out, int out_size, void* d_ws, size_t ws_size,
                              hipStream_t stream)
{
    const float* A      = (const float*)d_in[0];
    const float* hidden = (const float*)d_in[1];
    const int*   mask   = (const int*)d_in[2];
    const float* w_ih   = (const float*)d_in[3];
    const float* w_hh   = (const float*)d_in[4];
    const float* b_ih   = (const float*)d_in[5];
    const float* b_hh   = (const float*)d_in[6];
    const float* b_iah  = (const float*)d_in[7];
    const float* b_oah  = (const float*)d_in[8];
    const float* W_ein  = (const float*)d_in[9];
    const float* b_ein  = (const float*)d_in[10];
    const float* W_eout = (const float*)d_in[11];
    const float* b_eout = (const float*)d_in[12];
    const float* W_q0   = (const float*)d_in[13];
    const float* b_q0   = (const float*)d_in[14];
    const float* W_q1   = (const float*)d_in[15];
    const float* b_q1   = (const float*)d_in[16];
    const float* W_q2   = (const float*)d_in[17];
    const float* b_q2   = (const float*)d_in[18];
    float* out = (float*)d_out;
    char* ws = (char*)d_ws;

    // --- workspace layout (bytes) ---
    u16*   Et      = (u16*)(ws + 0);             // [256][32768] bf16 (E transposed)
    u16*   q12bf   = (u16*)(ws + 0);             // [32768][256] bf16 — aliases Et (dead after fuse)
    u16*   hnew_bf = (u16*)(ws + 33554432);      // [32768][128] bf16
    u16*   h_bf    = (u16*)(ws + 41943040);      // [32768][128] bf16
    u16*   W2bf    = (u16*)(ws + 50331648);      // [512][384]
    u16*   Wcat    = (u16*)(ws + 50724864);      // [256][128]
    u16*   Wq12    = (u16*)(ws + 50790400);      // [256][128]
    float* bias2   = (float*)(ws + 50855936);    // [512]
    float* biascat = (float*)(ws + 50857984);    // [256]
    float* biasq12 = (float*)(ws + 50859008);    // [256]

    // 1. weight prep + hidden cast
    k_prepw<<<4096, 256, 0, stream>>>(hidden, h_bf,
                                      w_ih, w_hh, b_ih, b_hh, b_iah, b_oah,
                                      W_ein, b_ein, W_eout, b_eout,
                                      W_q1, b_q1, W_q2, b_q2,
                                      W2bf, bias2, Wcat, biascat, Wq12, biasq12);

    // 2. E = h_bf @ [W_ein;W_eout]^T + bias, stored TRANSPOSED (Et[c][r])
    gemm_mfma<0, 2><<<dim3(256, 2, 1), 256, 0, stream>>>(
        h_bf, nullptr, HH, 0, 0, 0, 0,
        Wcat, HH, 0, 0, biascat,
        Et, 32768, 0, 0, HH, nullptr);

    // 3+4. FUSED msg + gates + GRU -> hnew (32 rows/block, grid 1024,
    //      50688 B LDS -> 3 blocks/CU)
    k_msg_gates<<<1024, 256, 0, stream>>>(A, Et, h_bf, W2bf, bias2, hnew_bf);

    // 5. q12 = hnew @ [W_q1;W_q2]^T + bias (bf16 out, overwrites Et region)
    gemm_mfma<0, 1><<<dim3(256, 2, 1), 256, 0, stream>>>(
        hnew_bf, nullptr, HH, 0, 0, 0, 0,
        Wq12, HH, 0, 0, biasq12,
        q12bf, 256, 0, 0, HH, nullptr);

    // 6. fused attention tail v3 (2 blocks/batch, 1024 threads)
    k_tail<<<dim3(BB, 2), 1024, 0, stream>>>(hnew_bf, mask, q12bf, W_q0, b_q0, out);
}

// Round 7
// 208.444 us; speedup vs baseline: 1.2848x; 1.2848x over previous
//
#include <hip/hip_runtime.h>
#include <cstdint>
#include <cstddef>

// Problem constants (B=128, S=256, H=128, HEADS=8, STEP=1)
#define BB   128
#define SS   256
#define HH   128
#define NH   8
#define DKK  16

typedef unsigned short u16;
typedef __attribute__((ext_vector_type(8))) short   sh8;    // 8 bf16 = 4 VGPRs (MFMA A/B frag)
typedef __attribute__((ext_vector_type(4))) float   f32x4;  // MFMA C/D frag

__device__ __forceinline__ float sigmoidf_(float x) { return 1.f / (1.f + expf(-x)); }

__device__ __forceinline__ u16 f2bf(float x) {
    union { float f; unsigned int u; } v; v.f = x;
    unsigned int r = (v.u + 0x7fffu + ((v.u >> 16) & 1u)) >> 16;  // RNE (finite inputs)
    return (u16)r;
}
__device__ __forceinline__ float bf2f(u16 u) {
    union { unsigned int u; float f; } v; v.u = ((unsigned int)u) << 16;
    return v.f;
}
// unpack lo/hi bf16 of a packed u32 (no addressable locals)
__device__ __forceinline__ float bflo(unsigned u) {
    union { unsigned u; float f; } v; v.u = u << 16; return v.f;
}
__device__ __forceinline__ float bfhi(unsigned u) {
    union { unsigned u; float f; } v; v.u = u & 0xffff0000u; return v.f;
}

// ===========================================================================
// GEMM: BK=32 single-buffer, 2 barriers/iter (round-0 known-good).
// Used for steps 2 and 3.  128x128 tile, 256 threads = 4 waves, wave 64x64
// (4x4 of 16x16x32).  B operands are B^T layout [N][K] bf16.
// XMODE: 0 = bf16 [M][K] row-major; 1 = fp32 [M][K] (convert while staging)
// OMODE: 1 = bf16 row-major; 2 = bf16 TRANSPOSED (Out[col*ldo + row])
// ===========================================================================
#define BKk 32
#define PK  40   // LDS K pitch in halves (32 + 8): conflict-free frag reads

template<int XMODE, int OMODE>
__global__ __launch_bounds__(256) void gemm_mfma(
    const void* __restrict__ Xa, const void* __restrict__ Xc, int ldx, int ldx1, int ksplit,
    long long sXb, long long sXh,
    const u16* __restrict__ Bw, int ldb, long long sBb, long long sBh,
    const float* __restrict__ bias,
    void* __restrict__ Out, long long ldo, long long sOb, long long sOh,
    int K, const u16* __restrict__ hid)
{
    __shared__ __align__(16) char smem[2 * 128 * PK * 2];  // 20480 B
    u16* As = (u16*)smem;
    u16* Bs = (u16*)(smem + 128 * PK * 2);

    const int t  = threadIdx.x;
    const int bm = blockIdx.x * 128;
    const int bn = blockIdx.y * 128;
    const long long zb = blockIdx.z >> 1, zh = blockIdx.z & 1;

    const u16* Bp = Bw + zb * sBb + zh * sBh;

    const int wave = t >> 6, lane = t & 63;
    const int wr = (wave >> 1) * 64, wc = (wave & 1) * 64;
    const int fm = lane & 15, fq = lane >> 4;

    f32x4 acc[4][4] = {};

    const int r0  = t >> 2, kk0 = (t & 3) * 8;  // bf16 staging: 8 halves (16B), 2 chunks
    const int r1  = t >> 3, kk1 = (t & 7) * 4;  // fp32 staging: 4 floats, 4 chunks

    // prefetch registers — named scalars only (keep them out of scratch!)
    uint4  px0, px1, pb0, pb1;
    float4 pf0, pf1, pf2, pf3;

#define LOADX32(K0)                                                                  \
    if (XMODE == 1) {                                                                \
        const float* Xf_ = (const float*)Xa + zb * sXb + zh * sXh;                   \
        const float* xp_ = Xf_ + (long long)(bm + r1) * ldx + (K0) + kk1;            \
        pf0 = *(const float4*)(xp_);                                                 \
        pf1 = *(const float4*)(xp_ + 32LL * ldx);                                    \
        pf2 = *(const float4*)(xp_ + 64LL * ldx);                                    \
        pf3 = *(const float4*)(xp_ + 96LL * ldx);                                    \
    } else {                                                                         \
        const u16* xp_ = (const u16*)Xa + (long long)(bm + r0) * ldx + (K0) + kk0;   \
        px0 = *(const uint4*)(xp_);                                                  \
        px1 = *(const uint4*)(xp_ + 64LL * ldx);                                     \
    }

#define LOADB32(K0)                                                                  \
    {                                                                                \
        const u16* bp_ = Bp + (long long)(bn + r0) * ldb + (K0) + kk0;               \
        pb0 = *(const uint4*)(bp_);                                                  \
        pb1 = *(const uint4*)(bp_ + 64LL * ldb);                                     \
    }

    LOADX32(0)
    LOADB32(0)

    for (int k0 = 0; k0 < K; k0 += BKk) {
        // ---- commit prefetched tile to LDS ----
        if (XMODE == 1) {
            ushort4 w0 = { f2bf(pf0.x), f2bf(pf0.y), f2bf(pf0.z), f2bf(pf0.w) };
            ushort4 w1 = { f2bf(pf1.x), f2bf(pf1.y), f2bf(pf1.z), f2bf(pf1.w) };
            ushort4 w2 = { f2bf(pf2.x), f2bf(pf2.y), f2bf(pf2.z), f2bf(pf2.w) };
            ushort4 w3 = { f2bf(pf3.x), f2bf(pf3.y), f2bf(pf3.z), f2bf(pf3.w) };
            *(ushort4*)&As[(r1     ) * PK + kk1] = w0;
            *(ushort4*)&As[(r1 + 32) * PK + kk1] = w1;
            *(ushort4*)&As[(r1 + 64) * PK + kk1] = w2;
            *(ushort4*)&As[(r1 + 96) * PK + kk1] = w3;
        } else {
            *(uint4*)&As[(r0     ) * PK + kk0] = px0;
            *(uint4*)&As[(r0 + 64) * PK + kk0] = px1;
        }
        *(uint4*)&Bs[(r0     ) * PK + kk0] = pb0;
        *(uint4*)&Bs[(r0 + 64) * PK + kk0] = pb1;
        __syncthreads();

        // ---- issue next-tile loads (hide HBM latency behind frag+MFMA) ----
        if (k0 + BKk < K) {
            LOADX32(k0 + BKk)
            LOADB32(k0 + BKk)
        }

        sh8 af[4], bfr[4];
        #pragma unroll
        for (int i = 0; i < 4; i++) af[i]  = *(const sh8*)&As[(wr + i * 16 + fm) * PK + fq * 8];
        #pragma unroll
        for (int j = 0; j < 4; j++) bfr[j] = *(const sh8*)&Bs[(wc + j * 16 + fm) * PK + fq * 8];
        #pragma unroll
        for (int i = 0; i < 4; i++)
            #pragma unroll
            for (int j = 0; j < 4; j++)
                acc[i][j] = __builtin_amdgcn_mfma_f32_16x16x32_bf16(af[i], bfr[j], acc[i][j], 0, 0, 0);
        __syncthreads();
    }
#undef LOADX32
#undef LOADB32

    // ---- epilogue (round-0 original): C layout col=lane&15, row=(lane>>4)*4+reg ----
    #pragma unroll
    for (int j = 0; j < 4; j++) {
        const int col = bn + wc + j * 16 + fm;
        const float bj = bias ? bias[col] : 0.f;
        #pragma unroll
        for (int i = 0; i < 4; i++) {
            const int row0 = bm + wr + i * 16 + fq * 4;
            if (OMODE == 1) {
                u16* O = (u16*)Out + zb * sOb + zh * sOh;
                #pragma unroll
                for (int r = 0; r < 4; r++)
                    O[(long long)(row0 + r) * ldo + col] = f2bf(acc[i][j][r] + bj);
            } else {  // OMODE == 2
                u16* O = (u16*)Out + zb * sOb + zh * sOh;
                ushort4 w = { f2bf(acc[i][j][0] + bj), f2bf(acc[i][j][1] + bj),
                              f2bf(acc[i][j][2] + bj), f2bf(acc[i][j][3] + bj) };
                *(ushort4*)&O[(long long)col * ldo + row0] = w;  // 4 consecutive rows
            }
        }
    }
}

// ===========================================================================
// GEMM variant 2: BK=64, DOUBLE-BUFFERED LDS, ONE barrier per K-step.
// Used ONLY for step 4 (gates, K=384, nt=6) — round-2/3 A/B showed this cut
// the gates dispatch 59.5 -> <40us while REGRESSING small-K call sites.
// XMODE 2 = concat along K: bf16 Xa (ld ldx) for k<ksplit, bf16 Xc (ld ldx1).
// OMODE 3 = fused GRU gate epilogue (W2 cols gate-interleaved, col=4c+g,
//           g: 0=r 1=i 2=n 3=hn); hnew = h - sig(gi)*(h - tanh(i_n +
//           sig(gr)*h_n)); h read from bf16 hid; coalesced stores.
// ===========================================================================
#define BKD  64
#define PKB  72            // LDS K pitch in halves (64 + 8)
#define ABUF (128 * PKB)   // halves per matrix per buffer (9216)
#define BUFH (2 * ABUF)    // halves per buffer (As+Bs) = 18432

template<int XMODE, int OMODE>
__global__ __launch_bounds__(256) void gemm_dbuf(
    const void* __restrict__ Xa, const void* __restrict__ Xc, int ldx, int ldx1, int ksplit,
    long long sXb, long long sXh,
    const u16* __restrict__ Bw, int ldb, long long sBb, long long sBh,
    const float* __restrict__ bias,
    void* __restrict__ Out, long long ldo, long long sOb, long long sOh,
    int K, const u16* __restrict__ hid)
{
    __shared__ __align__(16) char smem[2 * BUFH * 2];  // 73728 B (2 bufs x (As|Bs))
    u16* base = (u16*)smem;

    const int t  = threadIdx.x;
    const int bm = blockIdx.x * 128;
    const int bn = blockIdx.y * 128;

    const u16* Bp = Bw;

    const int wave = t >> 6, lane = t & 63;
    const int wr = (wave >> 1) * 64, wc = (wave & 1) * 64;
    const int fm = lane & 15, fq = lane >> 4;

    f32x4 acc[4][4] = {};

    // bf16 staging of a 128x64 tile: 8 chunks(16B)/row, 32 rows/pass, 4 passes
    const int rs = t >> 3, kcs = (t & 7) * 8;

    // prefetch registers — named scalars only
    uint4  px0, px1, px2, px3, pb0, pb1, pb2, pb3;

#define LOADX64(K0)                                                                  \
    if (XMODE == 2 && (K0) >= ksplit) {                                              \
        const u16* xp_ = (const u16*)Xc + (long long)(bm + rs) * ldx1               \
                         + ((K0) - ksplit) + kcs;                                    \
        px0 = *(const uint4*)(xp_);                                                  \
        px1 = *(const uint4*)(xp_ + 32LL * ldx1);                                    \
        px2 = *(const uint4*)(xp_ + 64LL * ldx1);                                    \
        px3 = *(const uint4*)(xp_ + 96LL * ldx1);                                    \
    } else {                                                                         \
        const u16* xp_ = (const u16*)Xa + (long long)(bm + rs) * ldx + (K0) + kcs;   \
        px0 = *(const uint4*)(xp_);                                                  \
        px1 = *(const uint4*)(xp_ + 32LL * ldx);                                     \
        px2 = *(const uint4*)(xp_ + 64LL * ldx);                                     \
        px3 = *(const uint4*)(xp_ + 96LL * ldx);                                     \
    }

#define LOADB64(K0)                                                                  \
    {                                                                                \
        const u16* bp_ = Bp + (long long)(bn + rs) * ldb + (K0) + kcs;               \
        pb0 = *(const uint4*)(bp_);                                                  \
        pb1 = *(const uint4*)(bp_ + 32LL * ldb);                                     \
        pb2 = *(const uint4*)(bp_ + 64LL * ldb);                                     \
        pb3 = *(const uint4*)(bp_ + 96LL * ldb);                                     \
    }

#define COMMIT64(Ad, Bd)                                                             \
    *(uint4*)&(Ad)[(rs     ) * PKB + kcs] = px0;                                     \
    *(uint4*)&(Ad)[(rs + 32) * PKB + kcs] = px1;                                     \
    *(uint4*)&(Ad)[(rs + 64) * PKB + kcs] = px2;                                     \
    *(uint4*)&(Ad)[(rs + 96) * PKB + kcs] = px3;                                     \
    *(uint4*)&(Bd)[(rs     ) * PKB + kcs] = pb0;                                     \
    *(uint4*)&(Bd)[(rs + 32) * PKB + kcs] = pb1;                                     \
    *(uint4*)&(Bd)[(rs + 64) * PKB + kcs] = pb2;                                     \
    *(uint4*)&(Bd)[(rs + 96) * PKB + kcs] = pb3;

    const int nt = K / BKD;
    int cur = 0;

    // prologue: stage tile 0 into buf0
    LOADX64(0)
    LOADB64(0)
    {
        u16* Ad = base;
        u16* Bd = base + ABUF;
        COMMIT64(Ad, Bd)
    }
    __syncthreads();

    for (int tt = 0; tt < nt; ++tt) {
        // ---- issue next-tile global loads first (hide latency under MFMA) ----
        if (tt + 1 < nt) {
            LOADX64((tt + 1) * BKD)
            LOADB64((tt + 1) * BKD)
        }

        // ---- 32 MFMA from buf[cur] (2 K-subtiles of 32) ----
        const u16* Ac = base + cur * BUFH;
        const u16* Bc = Ac + ABUF;
        #pragma unroll
        for (int ks = 0; ks < 2; ks++) {
            sh8 af[4], bfr[4];
            #pragma unroll
            for (int i = 0; i < 4; i++)
                af[i]  = *(const sh8*)&Ac[(wr + i * 16 + fm) * PKB + ks * 32 + fq * 8];
            #pragma unroll
            for (int j = 0; j < 4; j++)
                bfr[j] = *(const sh8*)&Bc[(wc + j * 16 + fm) * PKB + ks * 32 + fq * 8];
            #pragma unroll
            for (int i = 0; i < 4; i++)
                #pragma unroll
                for (int j = 0; j < 4; j++)
                    acc[i][j] = __builtin_amdgcn_mfma_f32_16x16x32_bf16(af[i], bfr[j], acc[i][j], 0, 0, 0);
        }

        // ---- commit prefetched tile into the other buffer ----
        if (tt + 1 < nt) {
            u16* Ad = base + (cur ^ 1) * BUFH;
            u16* Bd = Ad + ABUF;
            COMMIT64(Ad, Bd)
        }
        __syncthreads();
        cur ^= 1;
    }
#undef LOADX64
#undef LOADB64
#undef COMMIT64

    // ---- OMODE == 3: fused GRU epilogue, LDS-gather ----
    {
        float* g4s = (float*)smem;       // [32][132] fp32 = 16896 B (reuses bufs)
        const int chbase = bn >> 2;      // global channel base for this block
        const int s_t = t >> 3;          // 0..31 slab row
        const int cq  = t & 7;           // 0..7 channel quad
        u16* O = (u16*)Out;
        const int sbase = (wr ? 16 : 0) + fq * 4;
        #pragma unroll
        for (int i = 0; i < 4; i++) {
            // scatter acc+bias into LDS (rows of both wave halves -> 32 slab rows)
            #pragma unroll
            for (int j = 0; j < 4; j++) {
                const int q = wc + j * 16 + fm;
                const float bj = bias[bn + q];
                #pragma unroll
                for (int r = 0; r < 4; r++)
                    g4s[(sbase + r) * 132 + q] = acc[i][j][r] + bj;
            }
            __syncthreads();
            // gather: 1 row x 4 channels per thread, contiguous b128 reads
            {
                const int grow = bm + i * 16 + (s_t < 16 ? s_t : s_t + 48);
                const ushort4 hv = *(const ushort4*)&hid[(long long)grow * HH + chbase + 4 * cq];
                const float hvv[4] = { bf2f(hv.x), bf2f(hv.y), bf2f(hv.z), bf2f(hv.w) };
                ushort4 w;
                u16* wp = (u16*)&w;
                #pragma unroll
                for (int m = 0; m < 4; m++) {
                    f32x4 gv = *(const f32x4*)&g4s[s_t * 132 + 16 * cq + 4 * m];
                    float rg = sigmoidf_(gv[0]);
                    float ig = sigmoidf_(gv[1]);
                    float ng = tanhf(gv[2] + rg * gv[3]);
                    wp[m] = f2bf(hvv[m] - ig * (hvv[m] - ng));
                }
                *(ushort4*)&O[(long long)grow * ldo + chbase + 4 * cq] = w;
            }
            __syncthreads();
        }
    }
}

// ---------------------------------------------------------------------------
// Weight prep + hidden cast (one kernel, grid 4096x256).
//   h_bf = bf16(hidden)  (1048576 float4s)
//   W2bf [512x384], GATE-INTERLEAVED rows: np = 4c+g, g: 0=r 1=i 2=n 3=hn.
//   bias2[np] = gate bias + fold of (b_iah|b_oah) through w_ih (linear terms).
//   Wcat [256x128] = [W_ein; W_eout], biascat = [b_ein|b_eout]
//   Wq12 [256x128] = [W_q1; W_q2],    biasq12 = [b_q1|b_q2]
// ---------------------------------------------------------------------------
__global__ __launch_bounds__(256) void k_prepw(
    const float* __restrict__ hidden, u16* __restrict__ h_bf,
    const float* __restrict__ w_ih, const float* __restrict__ w_hh,
    const float* __restrict__ b_ih, const float* __restrict__ b_hh,
    const float* __restrict__ b_iah, const float* __restrict__ b_oah,
    const float* __restrict__ W_ein, const float* __restrict__ b_ein,
    const float* __restrict__ W_eout, const float* __restrict__ b_eout,
    const float* __restrict__ W_q1, const float* __restrict__ b_q1,
    const float* __restrict__ W_q2, const float* __restrict__ b_q2,
    u16* __restrict__ W2bf, float* __restrict__ bias2,
    u16* __restrict__ Wcat, float* __restrict__ biascat,
    u16* __restrict__ Wq12, float* __restrict__ biasq12)
{
    int idx = blockIdx.x * 256 + threadIdx.x;  // 0 .. 1048575
    {   // hidden -> bf16, 4 elems/thread
        float4 v = ((const float4*)hidden)[idx];
        ushort4 w = { f2bf(v.x), f2bf(v.y), f2bf(v.z), f2bf(v.w) };
        ((ushort4*)h_bf)[idx] = w;
    }
    if (idx < 512 * 384) {
        int np = idx / 384, kk = idx % 384;
        int c = np >> 2, g = np & 3;
        float v;
        if (g < 2)       v = (kk < 256) ? w_ih[(g * 128 + c) * 256 + kk]
                                        : w_hh[(g * 128 + c) * 128 + kk - 256];
        else if (g == 2) v = (kk < 256) ? w_ih[(256 + c) * 256 + kk] : 0.f;
        else             v = (kk < 256) ? 0.f : w_hh[(256 + c) * 128 + kk - 256];
        W2bf[idx] = f2bf(v);
    }
    if (idx < 256 * 128) {
        int n = idx >> 7, k = idx & 127;
        Wcat[idx] = f2bf(n < 128 ? W_ein[n * 128 + k] : W_eout[(n - 128) * 128 + k]);
        Wq12[idx] = f2bf(n < 128 ? W_q1[n * 128 + k]  : W_q2[(n - 128) * 128 + k]);
    }
    if (idx < 512) {
        int np = idx, c = np >> 2, g = np & 3;
        float s;
        if (g < 2)       s = b_ih[g * 128 + c] + b_hh[g * 128 + c];
        else if (g == 2) s = b_ih[256 + c];
        else             s = b_hh[256 + c];
        if (g < 3) {
            int n = (g < 2) ? g * 128 + c : 256 + c;
            for (int k = 0; k < 128; k++)
                s += w_ih[n * 256 + k] * b_iah[k] + w_ih[n * 256 + 128 + k] * b_oah[k];
        }
        bias2[np] = s;
    }
    if (idx < 256) {
        biascat[idx] = idx < 128 ? b_ein[idx] : b_eout[idx - 128];
        biasq12[idx] = idx < 128 ? b_q1[idx]  : b_q2[idx - 128];
    }
}

// ---------------------------------------------------------------------------
// k_tail v4: fused q12-GEMM + attention tail.  Grid (B, 2), 1024 threads
// (16 waves), ONE block per CU (grid 256 = 256 CUs).
//
// Round-6 lesson: fusing serial phases into fewer blocks loses (occupancy);
// fusing a whole dispatch into an EXISTING full-machine kernel wins if the
// added work is small.  Here each block computes its own q1 = hnew[b]@Wq1^T
// (full 128 ch, needed for scores) and q2 slice (its 64 readout cols) with
// MFMA — 48 MFMA/wave, trivial — killing the step-5 GEMM dispatch and the
// q12bf 16.8MB write + 16.8MB read.
//
// LDS (151,560 B, 1 block/CU):
//   [0       .. 69,632)  Hs  [256][136] bf16   (hnew tile)   } overlaid after
//   [69,632  ..121,856)  Wst [192][136] bf16   (Wq1|Wq2 slab)} GEMM by:
//   [0       .. 69,632)  q1s [256][136] bf16   (q1 + bias)
//   [69,632  ..106,496)  q2s [256][72]  bf16   (q2 slice + bias)
//   [121,856..151,560)   persistent tail scratch (red/red2/p_s/w_s/hs/q0s/nv)
//
// GEMM: wave w: rows (w>>2)*64..+64, pass1 q1 cols (w&3)*32..+32 (4x2 frags),
// pass2 q2 cols (w&3)*16..+16 (4x1 frags), K=128 in 4 steps; af shared
// between passes.  C layout col=lane&15, row=(lane>>4)*4+reg (verified).
// ---------------------------------------------------------------------------
#define HP 136   // Hs/Wst/q1s pitch in halves (17*8)
#define QP 72    // q2s pitch in halves

__global__ __launch_bounds__(1024) void k_tail(
    const u16* __restrict__ hnew_bf, const int* __restrict__ mask,
    const u16* __restrict__ Wq12, const float* __restrict__ biasq12,
    const float* __restrict__ Wq0, const float* __restrict__ bq0,
    float* __restrict__ out)
{
    __shared__ __align__(16) char smem[151560];
    u16*   Hs   = (u16*)smem;                    // [256][HP]
    u16*   Wst  = (u16*)(smem + 69632);          // [192][HP]
    u16*   q1s  = (u16*)smem;                    // [256][HP] overlay
    u16*   q2s  = (u16*)(smem + 69632);          // [256][QP] overlay
    float* red  = (float*)(smem + 121856);       // [1024]
    float* red2 = (float*)(smem + 125952);       // [1024][2]
    float* p_s  = (float*)(smem + 134144);       // [NH][SS]
    float* w_s  = (float*)(smem + 142336);       // [NH][SS]
    float* hs   = (float*)(smem + 150528);       // [HH]
    float* q0s  = (float*)(smem + 151040);       // [HH]
    int*   s_nv = (int*)(smem + 151552);

    const int b = blockIdx.x, chb = blockIdx.y, t = threadIdx.x;
    const int wave = t >> 6, lane = t & 63;
    const int fm = lane & 15, fq = lane >> 4;
    const int wrow = (wave >> 2) * 64;           // GEMM row base
    const int wc1  = (wave & 3) * 32;            // q1 col base
    const int wc2  = (wave & 3) * 16;            // q2 col base (local)

    // ---- stage hnew tile + weight slab ----
    {
        const int row = t >> 2, kc = (t & 3) * 32;
        const u16* hp = hnew_bf + ((size_t)b * SS + row) * HH + kc;
        uint4 v0 = *(const uint4*)(hp);
        uint4 v1 = *(const uint4*)(hp + 8);
        uint4 v2 = *(const uint4*)(hp + 16);
        uint4 v3 = *(const uint4*)(hp + 24);
        *(uint4*)&Hs[row * HP + kc     ] = v0;
        *(uint4*)&Hs[row * HP + kc + 8 ] = v1;
        *(uint4*)&Hs[row * HP + kc + 16] = v2;
        *(uint4*)&Hs[row * HP + kc + 24] = v3;
    }
    if (t < 768) {
        const int row = t >> 2, kc = (t & 3) * 32;
        const int gr = (row < 128) ? row : 128 + chb * 64 + (row - 128);
        const u16* wp = Wq12 + (size_t)gr * HH + kc;
        uint4 v0 = *(const uint4*)(wp);
        uint4 v1 = *(const uint4*)(wp + 8);
        uint4 v2 = *(const uint4*)(wp + 16);
        uint4 v3 = *(const uint4*)(wp + 24);
        *(uint4*)&Wst[row * HP + kc     ] = v0;
        *(uint4*)&Wst[row * HP + kc + 8 ] = v1;
        *(uint4*)&Wst[row * HP + kc + 16] = v2;
        *(uint4*)&Wst[row * HP + kc + 24] = v3;
    }
    __syncthreads();

    // ---- q12 GEMM: K=128 in 4 steps; af shared between q1 and q2 passes ----
    f32x4 a1[4][2] = {};
    f32x4 a2[4] = {};
    #pragma unroll
    for (int ks = 0; ks < 4; ks++) {
        sh8 af[4], b1[2], b2;
        #pragma unroll
        for (int i = 0; i < 4; i++)
            af[i] = *(const sh8*)&Hs[(wrow + i * 16 + fm) * HP + ks * 32 + fq * 8];
        #pragma unroll
        for (int j = 0; j < 2; j++)
            b1[j] = *(const sh8*)&Wst[(wc1 + j * 16 + fm) * HP + ks * 32 + fq * 8];
        b2 = *(const sh8*)&Wst[(128 + wc2 + fm) * HP + ks * 32 + fq * 8];
        #pragma unroll
        for (int i = 0; i < 4; i++) {
            #pragma unroll
            for (int j = 0; j < 2; j++)
                a1[i][j] = __builtin_amdgcn_mfma_f32_16x16x32_bf16(af[i], b1[j], a1[i][j], 0, 0, 0);
            a2[i] = __builtin_amdgcn_mfma_f32_16x16x32_bf16(af[i], b2, a2[i], 0, 0, 0);
        }
    }
    __syncthreads();   // all MFMA LDS reads done before overlay writes

    // ---- write q1s/q2s (bias folded) over the staging region ----
    {
        const float bq1a = biasq12[wc1 + fm];
        const float bq1b = biasq12[wc1 + 16 + fm];
        const float bq2  = biasq12[128 + chb * 64 + wc2 + fm];
        #pragma unroll
        for (int i = 0; i < 4; i++)
            #pragma unroll
            for (int r = 0; r < 4; r++) {
                const int row = wrow + i * 16 + fq * 4 + r;
                q1s[row * HP + wc1 + fm]      = f2bf(a1[i][0][r] + bq1a);
                q1s[row * HP + wc1 + 16 + fm] = f2bf(a1[i][1][r] + bq1b);
                q2s[row * QP + wc2 + fm]      = f2bf(a2[i][r] + bq2);
            }
    }
    __syncthreads();

    // ---- mask sum / last index: wave shfl-reduce ----
    if (t < 256) {
        int v = mask[b * SS + t];
        #pragma unroll
        for (int m = 1; m < 64; m <<= 1) v += __shfl_xor(v, m, 64);
        if ((t & 63) == 0) red[t >> 6] = (float)v;
    }
    __syncthreads();
    if (t == 0) *s_nv = (int)(red[0] + red[1] + red[2] + red[3]);
    __syncthreads();
    const int nv = *s_nv;
    const int last = (nv - 1) & (SS - 1);

    if (t < HH) hs[t] = bf2f(hnew_bf[((size_t)b * SS + last) * HH + t]);
    __syncthreads();

    // ---- q0 = h_last @ Wq0^T + bq0: n = t&127, K split 8 ways ----
    {
        const int n = t & 127, kh = t >> 7;  // kh 0..7, 16 k each
        const float* w = Wq0 + (size_t)n * HH + kh * 16;
        const float* h = hs + kh * 16;
        float s = 0.f;
        #pragma unroll
        for (int k = 0; k < 16; k++) s += h[k] * w[k];
        red[t] = s;
    }
    __syncthreads();
    if (t < HH) {
        float s = bq0[t];
        #pragma unroll
        for (int kh = 0; kh < 8; kh++) s += red[kh * 128 + t];
        q0s[t] = s;
    }
    __syncthreads();

    // ---- scores: j = t>>2 (256), q = t&3; thread computes heads 2q, 2q+1 ----
    {
        const int j = t >> 2, q = t & 3;
        const u16* q1r = q1s + j * HP + q * 32;
        uint4 va = *(const uint4*)(q1r);
        uint4 vb = *(const uint4*)(q1r + 8);
        uint4 vc = *(const uint4*)(q1r + 16);
        uint4 vd = *(const uint4*)(q1r + 24);
        const float* qa = q0s + q * 32;
        float s0 = qa[0]  * bflo(va.x) + qa[1]  * bfhi(va.x)
                 + qa[2]  * bflo(va.y) + qa[3]  * bfhi(va.y)
                 + qa[4]  * bflo(va.z) + qa[5]  * bfhi(va.z)
                 + qa[6]  * bflo(va.w) + qa[7]  * bfhi(va.w)
                 + qa[8]  * bflo(vb.x) + qa[9]  * bfhi(vb.x)
                 + qa[10] * bflo(vb.y) + qa[11] * bfhi(vb.y)
                 + qa[12] * bflo(vb.z) + qa[13] * bfhi(vb.z)
                 + qa[14] * bflo(vb.w) + qa[15] * bfhi(vb.w);
        float s1 = qa[16] * bflo(vc.x) + qa[17] * bfhi(vc.x)
                 + qa[18] * bflo(vc.y) + qa[19] * bfhi(vc.y)
                 + qa[20] * bflo(vc.z) + qa[21] * bfhi(vc.z)
                 + qa[22] * bflo(vc.w) + qa[23] * bfhi(vc.w)
                 + qa[24] * bflo(vd.x) + qa[25] * bfhi(vd.x)
                 + qa[26] * bflo(vd.y) + qa[27] * bfhi(vd.y)
                 + qa[28] * bflo(vd.z) + qa[29] * bfhi(vd.z)
                 + qa[30] * bflo(vd.w) + qa[31] * bfhi(vd.w);
        p_s[(2 * q) * SS + j]     = sigmoidf_(s0);
        p_s[(2 * q + 1) * SS + j] = sigmoidf_(s1);
    }
    __syncthreads();

    // ---- softmax over j per head (threads 0..255: 32 lanes/head, 8 vals) ----
    if (t < 256) {
        const int h = t >> 5, l = t & 31;
        float v[8], m = -1e30f;
        #pragma unroll
        for (int u = 0; u < 8; u++) { v[u] = p_s[h * SS + l * 8 + u]; m = fmaxf(m, v[u]); }
        #pragma unroll
        for (int msk = 1; msk < 32; msk <<= 1) m = fmaxf(m, __shfl_xor(m, msk, 32));
        float sum = 0.f;
        #pragma unroll
        for (int u = 0; u < 8; u++) { v[u] = expf(v[u] - m); sum += v[u]; }
        #pragma unroll
        for (int msk = 1; msk < 32; msk <<= 1) sum += __shfl_xor(sum, msk, 32);
        const float inv = 1.f / sum;
        #pragma unroll
        for (int u = 0; u < 8; u++) p_s[h * SS + l * 8 + u] = v[u] * inv;
    }
    __syncthreads();

    // ---- head softmax per j (threads 0..255) ----
    if (t < 256) {
        float e[NH], den = 0.f;
        #pragma unroll
        for (int h = 0; h < NH; h++) { e[h] = expf(2.f * p_s[h * SS + t]); den += e[h]; }
        const float inv = 1.f / den;
        #pragma unroll
        for (int h = 0; h < NH; h++) w_s[h * SS + t] = e[h] * inv;
    }
    __syncthreads();

    // ---- readout: this block owns cols [chb*64, chb*64+64).
    //      col pair cp = t&31 (2 cols via one uint LDS load), j split 32 ways ----
    {
        const int cp = t & 31, jq = t >> 5;
        const int col = chb * 64 + cp * 2;
        const int h0 = col >> 4;                    // col even -> both in same head
        float a0 = 0.f, a1v = 0.f;
        #pragma unroll
        for (int u = 0; u < 8; u++) {
            const int j = jq * 8 + u;
            const unsigned v = *(const unsigned*)&q2s[j * QP + cp * 2];
            const float w = w_s[h0 * SS + j];
            a0  += w * bflo(v);
            a1v += w * bfhi(v);
        }
        red2[t * 2 + 0] = a0;
        red2[t * 2 + 1] = a1v;
    }
    __syncthreads();
    // 32 col-pairs x 2 parities = 64 outputs for this block
    if (t < 64) {
        const int cp2 = t >> 1, par = t & 1;
        float s = 0.f;
        #pragma unroll
        for (int q = 0; q < 32; q++) s += red2[(q * 32 + cp2) * 2 + par];
        out[(size_t)b * HH + chb * 64 + cp2 * 2 + par] = s * (float)nv;
    }
}

// ---------------------------------------------------------------------------
extern "C" void kernel_launch(void* const* d_in, const int* in_sizes, int n_in,
                              void* d_out, int out_size, void* d_ws, size_t ws_size,
                              hipStream_t stream)
{
    const float* A      = (const float*)d_in[0];
    const float* hidden = (const float*)d_in[1];
    const int*   mask   = (const int*)d_in[2];
    const float* w_ih   = (const float*)d_in[3];
    const float* w_hh   = (const float*)d_in[4];
    const float* b_ih   = (const float*)d_in[5];
    const float* b_hh   = (const float*)d_in[6];
    const float* b_iah  = (const float*)d_in[7];
    const float* b_oah  = (const float*)d_in[8];
    const float* W_ein  = (const float*)d_in[9];
    const float* b_ein  = (const float*)d_in[10];
    const float* W_eout = (const float*)d_in[11];
    const float* b_eout = (const float*)d_in[12];
    const float* W_q0   = (const float*)d_in[13];
    const float* b_q0   = (const float*)d_in[14];
    const float* W_q1   = (const float*)d_in[15];
    const float* b_q1   = (const float*)d_in[16];
    const float* W_q2   = (const float*)d_in[17];
    const float* b_q2   = (const float*)d_in[18];
    float* out = (float*)d_out;
    char* ws = (char*)d_ws;

    // --- workspace layout (bytes) ---
    u16*   Et      = (u16*)(ws + 0);             // [256][32768] bf16 (E transposed)
    u16*   Mbuf    = (u16*)(ws + 16777216);      // [32768][256] bf16 (msg_in|msg_out)
    u16*   hnew_bf = (u16*)(ws + 33554432);      // [32768][128] bf16
    u16*   h_bf    = (u16*)(ws + 41943040);      // [32768][128] bf16
    u16*   W2bf    = (u16*)(ws + 50331648);      // [512][384]
    u16*   Wcat    = (u16*)(ws + 50724864);      // [256][128]
    u16*   Wq12    = (u16*)(ws + 50790400);      // [256][128]
    float* bias2   = (float*)(ws + 50855936);    // [512]
    float* biascat = (float*)(ws + 50857984);    // [256]
    float* biasq12 = (float*)(ws + 50859008);    // [256]

    // 1. weight prep + hidden cast
    k_prepw<<<4096, 256, 0, stream>>>(hidden, h_bf,
                                      w_ih, w_hh, b_ih, b_hh, b_iah, b_oah,
                                      W_ein, b_ein, W_eout, b_eout,
                                      W_q1, b_q1, W_q2, b_q2,
                                      W2bf, bias2, Wcat, biascat, Wq12, biasq12);

    // 2. E = h_bf @ [W_ein;W_eout]^T + bias, stored TRANSPOSED (Et[c][r])
    gemm_mfma<0, 2><<<dim3(256, 2, 1), 256, 0, stream>>>(
        h_bf, nullptr, HH, 0, 0, 0, 0,
        Wcat, HH, 0, 0, biascat,
        Et, 32768, 0, 0, HH, nullptr);

    // 3. msg: per (b,half): A-half[b] (fp32, ld 512) @ Et-slice^T -> Mbuf bf16
    gemm_mfma<1, 1><<<dim3(2, 1, 256), 256, 0, stream>>>(
        A, nullptr, 512, 0, 0, 131072LL, 256LL,
        Et, 32768, 256LL, 128LL * 32768LL, nullptr,
        Mbuf, 256, 65536LL, 128LL, SS, nullptr);

    // 4. gates = [Mbuf | h_bf] @ W2bf^T + bias2, fused GRU epilogue
    //    (LDS-gather, BK=64 double-buffered) -> hnew bf16 directly
    gemm_dbuf<2, 3><<<dim3(256, 4, 1), 256, 0, stream>>>(
        Mbuf, h_bf, 256, HH, 256, 0, 0,
        W2bf, 384, 0, 0, bias2,
        hnew_bf, HH, 0, 0, 384, h_bf);

    // 5+6. fused q12-GEMM + attention tail v4 (2 blocks/batch, 1024 threads)
    k_tail<<<dim3(BB, 2), 1024, 0, stream>>>(hnew_bf, mask, Wq12, biasq12,
                                             W_q0, b_q0, out);
}

// Round 8
// 207.043 us; speedup vs baseline: 1.2935x; 1.0068x over previous
//
#include <hip/hip_runtime.h>
#include <cstdint>
#include <cstddef>

// Problem constants (B=128, S=256, H=128, HEADS=8, STEP=1)
#define BB   128
#define SS   256
#define HH   128
#define NH   8
#define DKK  16

typedef unsigned short u16;
typedef __attribute__((ext_vector_type(8))) short   sh8;    // 8 bf16 = 4 VGPRs (MFMA A/B frag)
typedef __attribute__((ext_vector_type(4))) float   f32x4;  // MFMA C/D frag

__device__ __forceinline__ float sigmoidf_(float x) { return 1.f / (1.f + expf(-x)); }

__device__ __forceinline__ u16 f2bf(float x) {
    union { float f; unsigned int u; } v; v.f = x;
    unsigned int r = (v.u + 0x7fffu + ((v.u >> 16) & 1u)) >> 16;  // RNE (finite inputs)
    return (u16)r;
}
__device__ __forceinline__ float bf2f(u16 u) {
    union { unsigned int u; float f; } v; v.u = ((unsigned int)u) << 16;
    return v.f;
}
// unpack lo/hi bf16 of a packed u32 (no addressable locals)
__device__ __forceinline__ float bflo(unsigned u) {
    union { unsigned u; float f; } v; v.u = u << 16; return v.f;
}
__device__ __forceinline__ float bfhi(unsigned u) {
    union { unsigned u; float f; } v; v.u = u & 0xffff0000u; return v.f;
}

// ===========================================================================
// GEMM: BK=32 single-buffer, 2 barriers/iter (round-0 known-good).
// Used for step 2 ONLY (K=128, nt=2 — prologue-dominated; round-3 showed
// BK=64 dbuf REGRESSES this regime).  128x128 tile, 4 waves, wave 64x64.
// B operands are B^T layout [N][K] bf16.
// XMODE: 0 = bf16 [M][K] row-major; 1 = fp32 [M][K] (convert while staging)
// OMODE: 1 = bf16 row-major; 2 = bf16 TRANSPOSED (Out[col*ldo + row])
// ===========================================================================
#define BKk 32
#define PK  40   // LDS K pitch in halves (32 + 8): conflict-free frag reads

template<int XMODE, int OMODE>
__global__ __launch_bounds__(256) void gemm_mfma(
    const void* __restrict__ Xa, const void* __restrict__ Xc, int ldx, int ldx1, int ksplit,
    long long sXb, long long sXh,
    const u16* __restrict__ Bw, int ldb, long long sBb, long long sBh,
    const float* __restrict__ bias,
    void* __restrict__ Out, long long ldo, long long sOb, long long sOh,
    int K, const u16* __restrict__ hid)
{
    __shared__ __align__(16) char smem[2 * 128 * PK * 2];  // 20480 B
    u16* As = (u16*)smem;
    u16* Bs = (u16*)(smem + 128 * PK * 2);

    const int t  = threadIdx.x;
    const int bm = blockIdx.x * 128;
    const int bn = blockIdx.y * 128;
    const long long zb = blockIdx.z >> 1, zh = blockIdx.z & 1;

    const u16* Bp = Bw + zb * sBb + zh * sBh;

    const int wave = t >> 6, lane = t & 63;
    const int wr = (wave >> 1) * 64, wc = (wave & 1) * 64;
    const int fm = lane & 15, fq = lane >> 4;

    f32x4 acc[4][4] = {};

    const int r0  = t >> 2, kk0 = (t & 3) * 8;  // bf16 staging: 8 halves (16B), 2 chunks
    const int r1  = t >> 3, kk1 = (t & 7) * 4;  // fp32 staging: 4 floats, 4 chunks

    // prefetch registers — named scalars only (keep them out of scratch!)
    uint4  px0, px1, pb0, pb1;
    float4 pf0, pf1, pf2, pf3;

#define LOADX32(K0)                                                                  \
    if (XMODE == 1) {                                                                \
        const float* Xf_ = (const float*)Xa + zb * sXb + zh * sXh;                   \
        const float* xp_ = Xf_ + (long long)(bm + r1) * ldx + (K0) + kk1;            \
        pf0 = *(const float4*)(xp_);                                                 \
        pf1 = *(const float4*)(xp_ + 32LL * ldx);                                    \
        pf2 = *(const float4*)(xp_ + 64LL * ldx);                                    \
        pf3 = *(const float4*)(xp_ + 96LL * ldx);                                    \
    } else {                                                                         \
        const u16* xp_ = (const u16*)Xa + (long long)(bm + r0) * ldx + (K0) + kk0;   \
        px0 = *(const uint4*)(xp_);                                                  \
        px1 = *(const uint4*)(xp_ + 64LL * ldx);                                     \
    }

#define LOADB32(K0)                                                                  \
    {                                                                                \
        const u16* bp_ = Bp + (long long)(bn + r0) * ldb + (K0) + kk0;               \
        pb0 = *(const uint4*)(bp_);                                                  \
        pb1 = *(const uint4*)(bp_ + 64LL * ldb);                                     \
    }

    LOADX32(0)
    LOADB32(0)

    for (int k0 = 0; k0 < K; k0 += BKk) {
        // ---- commit prefetched tile to LDS ----
        if (XMODE == 1) {
            ushort4 w0 = { f2bf(pf0.x), f2bf(pf0.y), f2bf(pf0.z), f2bf(pf0.w) };
            ushort4 w1 = { f2bf(pf1.x), f2bf(pf1.y), f2bf(pf1.z), f2bf(pf1.w) };
            ushort4 w2 = { f2bf(pf2.x), f2bf(pf2.y), f2bf(pf2.z), f2bf(pf2.w) };
            ushort4 w3 = { f2bf(pf3.x), f2bf(pf3.y), f2bf(pf3.z), f2bf(pf3.w) };
            *(ushort4*)&As[(r1     ) * PK + kk1] = w0;
            *(ushort4*)&As[(r1 + 32) * PK + kk1] = w1;
            *(ushort4*)&As[(r1 + 64) * PK + kk1] = w2;
            *(ushort4*)&As[(r1 + 96) * PK + kk1] = w3;
        } else {
            *(uint4*)&As[(r0     ) * PK + kk0] = px0;
            *(uint4*)&As[(r0 + 64) * PK + kk0] = px1;
        }
        *(uint4*)&Bs[(r0     ) * PK + kk0] = pb0;
        *(uint4*)&Bs[(r0 + 64) * PK + kk0] = pb1;
        __syncthreads();

        // ---- issue next-tile loads (hide HBM latency behind frag+MFMA) ----
        if (k0 + BKk < K) {
            LOADX32(k0 + BKk)
            LOADB32(k0 + BKk)
        }

        sh8 af[4], bfr[4];
        #pragma unroll
        for (int i = 0; i < 4; i++) af[i]  = *(const sh8*)&As[(wr + i * 16 + fm) * PK + fq * 8];
        #pragma unroll
        for (int j = 0; j < 4; j++) bfr[j] = *(const sh8*)&Bs[(wc + j * 16 + fm) * PK + fq * 8];
        #pragma unroll
        for (int i = 0; i < 4; i++)
            #pragma unroll
            for (int j = 0; j < 4; j++)
                acc[i][j] = __builtin_amdgcn_mfma_f32_16x16x32_bf16(af[i], bfr[j], acc[i][j], 0, 0, 0);
        __syncthreads();
    }
#undef LOADX32
#undef LOADB32

    // ---- epilogue (round-0 original): C layout col=lane&15, row=(lane>>4)*4+reg ----
    #pragma unroll
    for (int j = 0; j < 4; j++) {
        const int col = bn + wc + j * 16 + fm;
        const float bj = bias ? bias[col] : 0.f;
        #pragma unroll
        for (int i = 0; i < 4; i++) {
            const int row0 = bm + wr + i * 16 + fq * 4;
            if (OMODE == 1) {
                u16* O = (u16*)Out + zb * sOb + zh * sOh;
                #pragma unroll
                for (int r = 0; r < 4; r++)
                    O[(long long)(row0 + r) * ldo + col] = f2bf(acc[i][j][r] + bj);
            } else {  // OMODE == 2
                u16* O = (u16*)Out + zb * sOb + zh * sOh;
                ushort4 w = { f2bf(acc[i][j][0] + bj), f2bf(acc[i][j][1] + bj),
                              f2bf(acc[i][j][2] + bj), f2bf(acc[i][j][3] + bj) };
                *(ushort4*)&O[(long long)col * ldo + row0] = w;  // 4 consecutive rows
            }
        }
    }
}

// ===========================================================================
// GEMM variant 2: BK=64, DOUBLE-BUFFERED LDS, ONE barrier per K-step.
// Used for step 4 (gates, K=384, nt=6: round-2/3 A/B, −20us) and NOW step 3
// (msg, K=256, nt=4: same nt>=4 regime; barriers 16 -> 5 per block).
// fp32 staging path (XMODE=1) is correctness-proven from round 3.
// Safety: iter i reads buf[cur], writes buf[cur^1]; all reads of buf[cur^1]
// finished before iter i-1's barrier (lgkmcnt precedes the MFMAs that
// precede the barrier) -> 1 barrier/iter is race-free.
// XMODE: 1 = fp32 [M][K] (convert while staging);
//        2 = concat along K: bf16 Xa (ld ldx) for k<ksplit, bf16 Xc after.
// OMODE: 1 = bf16 row-major (round-0 scattered epilogue, proven);
//        3 = fused GRU gate epilogue (gate-interleaved W2, verified).
// ===========================================================================
#define BKD  64
#define PKB  72            // LDS K pitch in halves (64 + 8)
#define ABUF (128 * PKB)   // halves per matrix per buffer (9216)
#define BUFH (2 * ABUF)    // halves per buffer (As+Bs) = 18432

template<int XMODE, int OMODE>
__global__ __launch_bounds__(256) void gemm_dbuf(
    const void* __restrict__ Xa, const void* __restrict__ Xc, int ldx, int ldx1, int ksplit,
    long long sXb, long long sXh,
    const u16* __restrict__ Bw, int ldb, long long sBb, long long sBh,
    const float* __restrict__ bias,
    void* __restrict__ Out, long long ldo, long long sOb, long long sOh,
    int K, const u16* __restrict__ hid)
{
    __shared__ __align__(16) char smem[2 * BUFH * 2];  // 73728 B (2 bufs x (As|Bs))
    u16* base = (u16*)smem;

    const int t  = threadIdx.x;
    const int bm = blockIdx.x * 128;
    const int bn = blockIdx.y * 128;
    const long long zb = blockIdx.z >> 1, zh = blockIdx.z & 1;

    const u16* Bp = Bw + zb * sBb + zh * sBh;

    const int wave = t >> 6, lane = t & 63;
    const int wr = (wave >> 1) * 64, wc = (wave & 1) * 64;
    const int fm = lane & 15, fq = lane >> 4;

    f32x4 acc[4][4] = {};

    // staging of a 128x64 tile:
    //   bf16: 8 chunks(16B)/row, 32 rows/pass, 4 passes  -> rs, kcs
    //   fp32: 16 float4/row, 16 rows/pass, 8 passes      -> rf, cf
    const int rs = t >> 3, kcs = (t & 7) * 8;
    const int rf = t >> 4, cf  = (t & 15) * 4;

    // prefetch registers — named scalars only
    uint4  px0, px1, px2, px3, pb0, pb1, pb2, pb3;
    float4 pf0, pf1, pf2, pf3, pf4, pf5, pf6, pf7;

#define LOADX64(K0)                                                                  \
    if (XMODE == 1) {                                                                \
        const float* Xf_ = (const float*)Xa + zb * sXb + zh * sXh;                   \
        const float* xp_ = Xf_ + (long long)(bm + rf) * ldx + (K0) + cf;             \
        pf0 = *(const float4*)(xp_);                                                 \
        pf1 = *(const float4*)(xp_ +  16LL * ldx);                                   \
        pf2 = *(const float4*)(xp_ +  32LL * ldx);                                   \
        pf3 = *(const float4*)(xp_ +  48LL * ldx);                                   \
        pf4 = *(const float4*)(xp_ +  64LL * ldx);                                   \
        pf5 = *(const float4*)(xp_ +  80LL * ldx);                                   \
        pf6 = *(const float4*)(xp_ +  96LL * ldx);                                   \
        pf7 = *(const float4*)(xp_ + 112LL * ldx);                                   \
    } else if (XMODE == 2 && (K0) >= ksplit) {                                       \
        const u16* xp_ = (const u16*)Xc + (long long)(bm + rs) * ldx1               \
                         + ((K0) - ksplit) + kcs;                                    \
        px0 = *(const uint4*)(xp_);                                                  \
        px1 = *(const uint4*)(xp_ + 32LL * ldx1);                                    \
        px2 = *(const uint4*)(xp_ + 64LL * ldx1);                                    \
        px3 = *(const uint4*)(xp_ + 96LL * ldx1);                                    \
    } else {                                                                         \
        const u16* xp_ = (const u16*)Xa + (long long)(bm + rs) * ldx + (K0) + kcs;   \
        px0 = *(const uint4*)(xp_);                                                  \
        px1 = *(const uint4*)(xp_ + 32LL * ldx);                                     \
        px2 = *(const uint4*)(xp_ + 64LL * ldx);                                     \
        px3 = *(const uint4*)(xp_ + 96LL * ldx);                                     \
    }

#define LOADB64(K0)                                                                  \
    {                                                                                \
        const u16* bp_ = Bp + (long long)(bn + rs) * ldb + (K0) + kcs;               \
        pb0 = *(const uint4*)(bp_);                                                  \
        pb1 = *(const uint4*)(bp_ + 32LL * ldb);                                     \
        pb2 = *(const uint4*)(bp_ + 64LL * ldb);                                     \
        pb3 = *(const uint4*)(bp_ + 96LL * ldb);                                     \
    }

#define COMMIT64(Ad, Bd)                                                             \
    if (XMODE == 1) {                                                                \
        ushort4 w0 = { f2bf(pf0.x), f2bf(pf0.y), f2bf(pf0.z), f2bf(pf0.w) };         \
        ushort4 w1 = { f2bf(pf1.x), f2bf(pf1.y), f2bf(pf1.z), f2bf(pf1.w) };         \
        ushort4 w2 = { f2bf(pf2.x), f2bf(pf2.y), f2bf(pf2.z), f2bf(pf2.w) };         \
        ushort4 w3 = { f2bf(pf3.x), f2bf(pf3.y), f2bf(pf3.z), f2bf(pf3.w) };         \
        ushort4 w4 = { f2bf(pf4.x), f2bf(pf4.y), f2bf(pf4.z), f2bf(pf4.w) };         \
        ushort4 w5 = { f2bf(pf5.x), f2bf(pf5.y), f2bf(pf5.z), f2bf(pf5.w) };         \
        ushort4 w6 = { f2bf(pf6.x), f2bf(pf6.y), f2bf(pf6.z), f2bf(pf6.w) };         \
        ushort4 w7 = { f2bf(pf7.x), f2bf(pf7.y), f2bf(pf7.z), f2bf(pf7.w) };         \
        *(ushort4*)&(Ad)[(rf      ) * PKB + cf] = w0;                                \
        *(ushort4*)&(Ad)[(rf +  16) * PKB + cf] = w1;                                \
        *(ushort4*)&(Ad)[(rf +  32) * PKB + cf] = w2;                                \
        *(ushort4*)&(Ad)[(rf +  48) * PKB + cf] = w3;                                \
        *(ushort4*)&(Ad)[(rf +  64) * PKB + cf] = w4;                                \
        *(ushort4*)&(Ad)[(rf +  80) * PKB + cf] = w5;                                \
        *(ushort4*)&(Ad)[(rf +  96) * PKB + cf] = w6;                                \
        *(ushort4*)&(Ad)[(rf + 112) * PKB + cf] = w7;                                \
    } else {                                                                         \
        *(uint4*)&(Ad)[(rs     ) * PKB + kcs] = px0;                                 \
        *(uint4*)&(Ad)[(rs + 32) * PKB + kcs] = px1;                                 \
        *(uint4*)&(Ad)[(rs + 64) * PKB + kcs] = px2;                                 \
        *(uint4*)&(Ad)[(rs + 96) * PKB + kcs] = px3;                                 \
    }                                                                                \
    *(uint4*)&(Bd)[(rs     ) * PKB + kcs] = pb0;                                     \
    *(uint4*)&(Bd)[(rs + 32) * PKB + kcs] = pb1;                                     \
    *(uint4*)&(Bd)[(rs + 64) * PKB + kcs] = pb2;                                     \
    *(uint4*)&(Bd)[(rs + 96) * PKB + kcs] = pb3;

    const int nt = K / BKD;
    int cur = 0;

    // prologue: stage tile 0 into buf0
    LOADX64(0)
    LOADB64(0)
    {
        u16* Ad = base;
        u16* Bd = base + ABUF;
        COMMIT64(Ad, Bd)
    }
    __syncthreads();

    for (int tt = 0; tt < nt; ++tt) {
        // ---- issue next-tile global loads first (hide latency under MFMA) ----
        if (tt + 1 < nt) {
            LOADX64((tt + 1) * BKD)
            LOADB64((tt + 1) * BKD)
        }

        // ---- 32 MFMA from buf[cur] (2 K-subtiles of 32) ----
        const u16* Ac = base + cur * BUFH;
        const u16* Bc = Ac + ABUF;
        #pragma unroll
        for (int ks = 0; ks < 2; ks++) {
            sh8 af[4], bfr[4];
            #pragma unroll
            for (int i = 0; i < 4; i++)
                af[i]  = *(const sh8*)&Ac[(wr + i * 16 + fm) * PKB + ks * 32 + fq * 8];
            #pragma unroll
            for (int j = 0; j < 4; j++)
                bfr[j] = *(const sh8*)&Bc[(wc + j * 16 + fm) * PKB + ks * 32 + fq * 8];
            #pragma unroll
            for (int i = 0; i < 4; i++)
                #pragma unroll
                for (int j = 0; j < 4; j++)
                    acc[i][j] = __builtin_amdgcn_mfma_f32_16x16x32_bf16(af[i], bfr[j], acc[i][j], 0, 0, 0);
        }

        // ---- commit prefetched tile into the other buffer ----
        if (tt + 1 < nt) {
            u16* Ad = base + (cur ^ 1) * BUFH;
            u16* Bd = Ad + ABUF;
            COMMIT64(Ad, Bd)
        }
        __syncthreads();
        cur ^= 1;
    }
#undef LOADX64
#undef LOADB64
#undef COMMIT64

    if (OMODE != 3) {
        // ---- round-0 scattered epilogue (proven): col=lane&15, row=(lane>>4)*4+reg ----
        u16* O = (u16*)Out + zb * sOb + zh * sOh;
        #pragma unroll
        for (int j = 0; j < 4; j++) {
            const int col = bn + wc + j * 16 + fm;
            const float bj = bias ? bias[col] : 0.f;
            #pragma unroll
            for (int i = 0; i < 4; i++) {
                const int row0 = bm + wr + i * 16 + fq * 4;
                #pragma unroll
                for (int r = 0; r < 4; r++)
                    O[(long long)(row0 + r) * ldo + col] = f2bf(acc[i][j][r] + bj);
            }
        }
    } else {
        // ---- OMODE == 3: fused GRU epilogue, LDS-gather (verified) ----
        float* g4s = (float*)smem;       // [32][132] fp32 = 16896 B (reuses bufs)
        const int chbase = bn >> 2;      // global channel base for this block
        const int s_t = t >> 3;          // 0..31 slab row
        const int cq  = t & 7;           // 0..7 channel quad
        u16* O = (u16*)Out;
        const int sbase = (wr ? 16 : 0) + fq * 4;
        #pragma unroll
        for (int i = 0; i < 4; i++) {
            // scatter acc+bias into LDS (rows of both wave halves -> 32 slab rows)
            #pragma unroll
            for (int j = 0; j < 4; j++) {
                const int q = wc + j * 16 + fm;
                const float bj = bias[bn + q];
                #pragma unroll
                for (int r = 0; r < 4; r++)
                    g4s[(sbase + r) * 132 + q] = acc[i][j][r] + bj;
            }
            __syncthreads();
            // gather: 1 row x 4 channels per thread, contiguous b128 reads
            {
                const int grow = bm + i * 16 + (s_t < 16 ? s_t : s_t + 48);
                const ushort4 hv = *(const ushort4*)&hid[(long long)grow * HH + chbase + 4 * cq];
                const float hvv[4] = { bf2f(hv.x), bf2f(hv.y), bf2f(hv.z), bf2f(hv.w) };
                ushort4 w;
                u16* wp = (u16*)&w;
                #pragma unroll
                for (int m = 0; m < 4; m++) {
                    f32x4 gv = *(const f32x4*)&g4s[s_t * 132 + 16 * cq + 4 * m];
                    float rg = sigmoidf_(gv[0]);
                    float ig = sigmoidf_(gv[1]);
                    float ng = tanhf(gv[2] + rg * gv[3]);
                    wp[m] = f2bf(hvv[m] - ig * (hvv[m] - ng));
                }
                *(ushort4*)&O[(long long)grow * ldo + chbase + 4 * cq] = w;
            }
            __syncthreads();
        }
    }
}

// ---------------------------------------------------------------------------
// Weight prep + hidden cast (one kernel, grid 4096x256).
//   h_bf = bf16(hidden)  (1048576 float4s)
//   W2bf [512x384], GATE-INTERLEAVED rows: np = 4c+g, g: 0=r 1=i 2=n 3=hn.
//   bias2[np] = gate bias + fold of (b_iah|b_oah) through w_ih (linear terms).
//   Wcat [256x128] = [W_ein; W_eout], biascat = [b_ein|b_eout]
//   Wq12 [256x128] = [W_q1; W_q2],    biasq12 = [b_q1|b_q2]
// ---------------------------------------------------------------------------
__global__ __launch_bounds__(256) void k_prepw(
    const float* __restrict__ hidden, u16* __restrict__ h_bf,
    const float* __restrict__ w_ih, const float* __restrict__ w_hh,
    const float* __restrict__ b_ih, const float* __restrict__ b_hh,
    const float* __restrict__ b_iah, const float* __restrict__ b_oah,
    const float* __restrict__ W_ein, const float* __restrict__ b_ein,
    const float* __restrict__ W_eout, const float* __restrict__ b_eout,
    const float* __restrict__ W_q1, const float* __restrict__ b_q1,
    const float* __restrict__ W_q2, const float* __restrict__ b_q2,
    u16* __restrict__ W2bf, float* __restrict__ bias2,
    u16* __restrict__ Wcat, float* __restrict__ biascat,
    u16* __restrict__ Wq12, float* __restrict__ biasq12)
{
    int idx = blockIdx.x * 256 + threadIdx.x;  // 0 .. 1048575
    {   // hidden -> bf16, 4 elems/thread
        float4 v = ((const float4*)hidden)[idx];
        ushort4 w = { f2bf(v.x), f2bf(v.y), f2bf(v.z), f2bf(v.w) };
        ((ushort4*)h_bf)[idx] = w;
    }
    if (idx < 512 * 384) {
        int np = idx / 384, kk = idx % 384;
        int c = np >> 2, g = np & 3;
        float v;
        if (g < 2)       v = (kk < 256) ? w_ih[(g * 128 + c) * 256 + kk]
                                        : w_hh[(g * 128 + c) * 128 + kk - 256];
        else if (g == 2) v = (kk < 256) ? w_ih[(256 + c) * 256 + kk] : 0.f;
        else             v = (kk < 256) ? 0.f : w_hh[(256 + c) * 128 + kk - 256];
        W2bf[idx] = f2bf(v);
    }
    if (idx < 256 * 128) {
        int n = idx >> 7, k = idx & 127;
        Wcat[idx] = f2bf(n < 128 ? W_ein[n * 128 + k] : W_eout[(n - 128) * 128 + k]);
        Wq12[idx] = f2bf(n < 128 ? W_q1[n * 128 + k]  : W_q2[(n - 128) * 128 + k]);
    }
    if (idx < 512) {
        int np = idx, c = np >> 2, g = np & 3;
        float s;
        if (g < 2)       s = b_ih[g * 128 + c] + b_hh[g * 128 + c];
        else if (g == 2) s = b_ih[256 + c];
        else             s = b_hh[256 + c];
        if (g < 3) {
            int n = (g < 2) ? g * 128 + c : 256 + c;
            for (int k = 0; k < 128; k++)
                s += w_ih[n * 256 + k] * b_iah[k] + w_ih[n * 256 + 128 + k] * b_oah[k];
        }
        bias2[np] = s;
    }
    if (idx < 256) {
        biascat[idx] = idx < 128 ? b_ein[idx] : b_eout[idx - 128];
        biasq12[idx] = idx < 128 ? b_q1[idx]  : b_q2[idx - 128];
    }
}

// ---------------------------------------------------------------------------
// k_tail v4: fused q12-GEMM + attention tail.  Grid (B, 2), 1024 threads
// (16 waves), one block per CU.  Each block computes its own q1 (full 128 ch)
// and q2 slice (its 64 readout cols) from hnew via MFMA, then runs the
// verified score/softmax/readout phases.  Kills the step-5 GEMM dispatch and
// the q12bf 16.8MB write + 16.8MB read.  (Round-7: part of 215->208 win.)
// ---------------------------------------------------------------------------
#define HP 136   // Hs/Wst/q1s pitch in halves (17*8)
#define QP 72    // q2s pitch in halves

__global__ __launch_bounds__(1024) void k_tail(
    const u16* __restrict__ hnew_bf, const int* __restrict__ mask,
    const u16* __restrict__ Wq12, const float* __restrict__ biasq12,
    const float* __restrict__ Wq0, const float* __restrict__ bq0,
    float* __restrict__ out)
{
    __shared__ __align__(16) char smem[151560];
    u16*   Hs   = (u16*)smem;                    // [256][HP]
    u16*   Wst  = (u16*)(smem + 69632);          // [192][HP]
    u16*   q1s  = (u16*)smem;                    // [256][HP] overlay
    u16*   q2s  = (u16*)(smem + 69632);          // [256][QP] overlay
    float* red  = (float*)(smem + 121856);       // [1024]
    float* red2 = (float*)(smem + 125952);       // [1024][2]
    float* p_s  = (float*)(smem + 134144);       // [NH][SS]
    float* w_s  = (float*)(smem + 142336);       // [NH][SS]
    float* hs   = (float*)(smem + 150528);       // [HH]
    float* q0s  = (float*)(smem + 151040);       // [HH]
    int*   s_nv = (int*)(smem + 151552);

    const int b = blockIdx.x, chb = blockIdx.y, t = threadIdx.x;
    const int wave = t >> 6, lane = t & 63;
    const int fm = lane & 15, fq = lane >> 4;
    const int wrow = (wave >> 2) * 64;           // GEMM row base
    const int wc1  = (wave & 3) * 32;            // q1 col base
    const int wc2  = (wave & 3) * 16;            // q2 col base (local)

    // ---- stage hnew tile + weight slab ----
    {
        const int row = t >> 2, kc = (t & 3) * 32;
        const u16* hp = hnew_bf + ((size_t)b * SS + row) * HH + kc;
        uint4 v0 = *(const uint4*)(hp);
        uint4 v1 = *(const uint4*)(hp + 8);
        uint4 v2 = *(const uint4*)(hp + 16);
        uint4 v3 = *(const uint4*)(hp + 24);
        *(uint4*)&Hs[row * HP + kc     ] = v0;
        *(uint4*)&Hs[row * HP + kc + 8 ] = v1;
        *(uint4*)&Hs[row * HP + kc + 16] = v2;
        *(uint4*)&Hs[row * HP + kc + 24] = v3;
    }
    if (t < 768) {
        const int row = t >> 2, kc = (t & 3) * 32;
        const int gr = (row < 128) ? row : 128 + chb * 64 + (row - 128);
        const u16* wp = Wq12 + (size_t)gr * HH + kc;
        uint4 v0 = *(const uint4*)(wp);
        uint4 v1 = *(const uint4*)(wp + 8);
        uint4 v2 = *(const uint4*)(wp + 16);
        uint4 v3 = *(const uint4*)(wp + 24);
        *(uint4*)&Wst[row * HP + kc     ] = v0;
        *(uint4*)&Wst[row * HP + kc + 8 ] = v1;
        *(uint4*)&Wst[row * HP + kc + 16] = v2;
        *(uint4*)&Wst[row * HP + kc + 24] = v3;
    }
    __syncthreads();

    // ---- q12 GEMM: K=128 in 4 steps; af shared between q1 and q2 passes ----
    f32x4 a1[4][2] = {};
    f32x4 a2[4] = {};
    #pragma unroll
    for (int ks = 0; ks < 4; ks++) {
        sh8 af[4], b1[2], b2;
        #pragma unroll
        for (int i = 0; i < 4; i++)
            af[i] = *(const sh8*)&Hs[(wrow + i * 16 + fm) * HP + ks * 32 + fq * 8];
        #pragma unroll
        for (int j = 0; j < 2; j++)
            b1[j] = *(const sh8*)&Wst[(wc1 + j * 16 + fm) * HP + ks * 32 + fq * 8];
        b2 = *(const sh8*)&Wst[(128 + wc2 + fm) * HP + ks * 32 + fq * 8];
        #pragma unroll
        for (int i = 0; i < 4; i++) {
            #pragma unroll
            for (int j = 0; j < 2; j++)
                a1[i][j] = __builtin_amdgcn_mfma_f32_16x16x32_bf16(af[i], b1[j], a1[i][j], 0, 0, 0);
            a2[i] = __builtin_amdgcn_mfma_f32_16x16x32_bf16(af[i], b2, a2[i], 0, 0, 0);
        }
    }
    __syncthreads();   // all MFMA LDS reads done before overlay writes

    // ---- write q1s/q2s (bias folded) over the staging region ----
    {
        const float bq1a = biasq12[wc1 + fm];
        const float bq1b = biasq12[wc1 + 16 + fm];
        const float bq2  = biasq12[128 + chb * 64 + wc2 + fm];
        #pragma unroll
        for (int i = 0; i < 4; i++)
            #pragma unroll
            for (int r = 0; r < 4; r++) {
                const int row = wrow + i * 16 + fq * 4 + r;
                q1s[row * HP + wc1 + fm]      = f2bf(a1[i][0][r] + bq1a);
                q1s[row * HP + wc1 + 16 + fm] = f2bf(a1[i][1][r] + bq1b);
                q2s[row * QP + wc2 + fm]      = f2bf(a2[i][r] + bq2);
            }
    }
    __syncthreads();

    // ---- mask sum / last index: wave shfl-reduce ----
    if (t < 256) {
        int v = mask[b * SS + t];
        #pragma unroll
        for (int m = 1; m < 64; m <<= 1) v += __shfl_xor(v, m, 64);
        if ((t & 63) == 0) red[t >> 6] = (float)v;
    }
    __syncthreads();
    if (t == 0) *s_nv = (int)(red[0] + red[1] + red[2] + red[3]);
    __syncthreads();
    const int nv = *s_nv;
    const int last = (nv - 1) & (SS - 1);

    if (t < HH) hs[t] = bf2f(hnew_bf[((size_t)b * SS + last) * HH + t]);
    __syncthreads();

    // ---- q0 = h_last @ Wq0^T + bq0: n = t&127, K split 8 ways ----
    {
        const int n = t & 127, kh = t >> 7;  // kh 0..7, 16 k each
        const float* w = Wq0 + (size_t)n * HH + kh * 16;
        const float* h = hs + kh * 16;
        float s = 0.f;
        #pragma unroll
        for (int k = 0; k < 16; k++) s += h[k] * w[k];
        red[t] = s;
    }
    __syncthreads();
    if (t < HH) {
        float s = bq0[t];
        #pragma unroll
        for (int kh = 0; kh < 8; kh++) s += red[kh * 128 + t];
        q0s[t] = s;
    }
    __syncthreads();

    // ---- scores: j = t>>2 (256), q = t&3; thread computes heads 2q, 2q+1 ----
    {
        const int j = t >> 2, q = t & 3;
        const u16* q1r = q1s + j * HP + q * 32;
        uint4 va = *(const uint4*)(q1r);
        uint4 vb = *(const uint4*)(q1r + 8);
        uint4 vc = *(const uint4*)(q1r + 16);
        uint4 vd = *(const uint4*)(q1r + 24);
        const float* qa = q0s + q * 32;
        float s0 = qa[0]  * bflo(va.x) + qa[1]  * bfhi(va.x)
                 + qa[2]  * bflo(va.y) + qa[3]  * bfhi(va.y)
                 + qa[4]  * bflo(va.z) + qa[5]  * bfhi(va.z)
                 + qa[6]  * bflo(va.w) + qa[7]  * bfhi(va.w)
                 + qa[8]  * bflo(vb.x) + qa[9]  * bfhi(vb.x)
                 + qa[10] * bflo(vb.y) + qa[11] * bfhi(vb.y)
                 + qa[12] * bflo(vb.z) + qa[13] * bfhi(vb.z)
                 + qa[14] * bflo(vb.w) + qa[15] * bfhi(vb.w);
        float s1 = qa[16] * bflo(vc.x) + qa[17] * bfhi(vc.x)
                 + qa[18] * bflo(vc.y) + qa[19] * bfhi(vc.y)
                 + qa[20] * bflo(vc.z) + qa[21] * bfhi(vc.z)
                 + qa[22] * bflo(vc.w) + qa[23] * bfhi(vc.w)
                 + qa[24] * bflo(vd.x) + qa[25] * bfhi(vd.x)
                 + qa[26] * bflo(vd.y) + qa[27] * bfhi(vd.y)
                 + qa[28] * bflo(vd.z) + qa[29] * bfhi(vd.z)
                 + qa[30] * bflo(vd.w) + qa[31] * bfhi(vd.w);
        p_s[(2 * q) * SS + j]     = sigmoidf_(s0);
        p_s[(2 * q + 1) * SS + j] = sigmoidf_(s1);
    }
    __syncthreads();

    // ---- softmax over j per head (threads 0..255: 32 lanes/head, 8 vals) ----
    if (t < 256) {
        const int h = t >> 5, l = t & 31;
        float v[8], m = -1e30f;
        #pragma unroll
        for (int u = 0; u < 8; u++) { v[u] = p_s[h * SS + l * 8 + u]; m = fmaxf(m, v[u]); }
        #pragma unroll
        for (int msk = 1; msk < 32; msk <<= 1) m = fmaxf(m, __shfl_xor(m, msk, 32));
        float sum = 0.f;
        #pragma unroll
        for (int u = 0; u < 8; u++) { v[u] = expf(v[u] - m); sum += v[u]; }
        #pragma unroll
        for (int msk = 1; msk < 32; msk <<= 1) sum += __shfl_xor(sum, msk, 32);
        const float inv = 1.f / sum;
        #pragma unroll
        for (int u = 0; u < 8; u++) p_s[h * SS + l * 8 + u] = v[u] * inv;
    }
    __syncthreads();

    // ---- head softmax per j (threads 0..255) ----
    if (t < 256) {
        float e[NH], den = 0.f;
        #pragma unroll
        for (int h = 0; h < NH; h++) { e[h] = expf(2.f * p_s[h * SS + t]); den += e[h]; }
        const float inv = 1.f / den;
        #pragma unroll
        for (int h = 0; h < NH; h++) w_s[h * SS + t] = e[h] * inv;
    }
    __syncthreads();

    // ---- readout: this block owns cols [chb*64, chb*64+64).
    //      col pair cp = t&31 (2 cols via one uint LDS load), j split 32 ways ----
    {
        const int cp = t & 31, jq = t >> 5;
        const int col = chb * 64 + cp * 2;
        const int h0 = col >> 4;                    // col even -> both in same head
        float a0 = 0.f, a1v = 0.f;
        #pragma unroll
        for (int u = 0; u < 8; u++) {
            const int j = jq * 8 + u;
            const unsigned v = *(const unsigned*)&q2s[j * QP + cp * 2];
            const float w = w_s[h0 * SS + j];
            a0  += w * bflo(v);
            a1v += w * bfhi(v);
        }
        red2[t * 2 + 0] = a0;
        red2[t * 2 + 1] = a1v;
    }
    __syncthreads();
    // 32 col-pairs x 2 parities = 64 outputs for this block
    if (t < 64) {
        const int cp2 = t >> 1, par = t & 1;
        float s = 0.f;
        #pragma unroll
        for (int q = 0; q < 32; q++) s += red2[(q * 32 + cp2) * 2 + par];
        out[(size_t)b * HH + chb * 64 + cp2 * 2 + par] = s * (float)nv;
    }
}

// ---------------------------------------------------------------------------
extern "C" void kernel_launch(void* const* d_in, const int* in_sizes, int n_in,
                              void* d_out, int out_size, void* d_ws, size_t ws_size,
                              hipStream_t stream)
{
    const float* A      = (const float*)d_in[0];
    const float* hidden = (const float*)d_in[1];
    const int*   mask   = (const int*)d_in[2];
    const float* w_ih   = (const float*)d_in[3];
    const float* w_hh   = (const float*)d_in[4];
    const float* b_ih   = (const float*)d_in[5];
    const float* b_hh   = (const float*)d_in[6];
    const float* b_iah  = (const float*)d_in[7];
    const float* b_oah  = (const float*)d_in[8];
    const float* W_ein  = (const float*)d_in[9];
    const float* b_ein  = (const float*)d_in[10];
    const float* W_eout = (const float*)d_in[11];
    const float* b_eout = (const float*)d_in[12];
    const float* W_q0   = (const float*)d_in[13];
    const float* b_q0   = (const float*)d_in[14];
    const float* W_q1   = (const float*)d_in[15];
    const float* b_q1   = (const float*)d_in[16];
    const float* W_q2   = (const float*)d_in[17];
    const float* b_q2   = (const float*)d_in[18];
    float* out = (float*)d_out;
    char* ws = (char*)d_ws;

    // --- workspace layout (bytes) ---
    u16*   Et      = (u16*)(ws + 0);             // [256][32768] bf16 (E transposed)
    u16*   Mbuf    = (u16*)(ws + 16777216);      // [32768][256] bf16 (msg_in|msg_out)
    u16*   hnew_bf = (u16*)(ws + 33554432);      // [32768][128] bf16
    u16*   h_bf    = (u16*)(ws + 41943040);      // [32768][128] bf16
    u16*   W2bf    = (u16*)(ws + 50331648);      // [512][384]
    u16*   Wcat    = (u16*)(ws + 50724864);      // [256][128]
    u16*   Wq12    = (u16*)(ws + 50790400);      // [256][128]
    float* bias2   = (float*)(ws + 50855936);    // [512]
    float* biascat = (float*)(ws + 50857984);    // [256]
    float* biasq12 = (float*)(ws + 50859008);    // [256]

    // 1. weight prep + hidden cast
    k_prepw<<<4096, 256, 0, stream>>>(hidden, h_bf,
                                      w_ih, w_hh, b_ih, b_hh, b_iah, b_oah,
                                      W_ein, b_ein, W_eout, b_eout,
                                      W_q1, b_q1, W_q2, b_q2,
                                      W2bf, bias2, Wcat, biascat, Wq12, biasq12);

    // 2. E = h_bf @ [W_ein;W_eout]^T + bias, stored TRANSPOSED (Et[c][r])
    //    (K=128, nt=2 — stays on the BK=32 kernel; dbuf regresses nt=2)
    gemm_mfma<0, 2><<<dim3(256, 2, 1), 256, 0, stream>>>(
        h_bf, nullptr, HH, 0, 0, 0, 0,
        Wcat, HH, 0, 0, biascat,
        Et, 32768, 0, 0, HH, nullptr);

    // 3. msg: A-half[b] (fp32) @ Et-slice^T -> Mbuf bf16
    //    NOW BK=64 double-buffered (K=256, nt=4 — the regime where dbuf won)
    gemm_dbuf<1, 1><<<dim3(2, 1, 256), 256, 0, stream>>>(
        A, nullptr, 512, 0, 0, 131072LL, 256LL,
        Et, 32768, 256LL, 128LL * 32768LL, nullptr,
        Mbuf, 256, 65536LL, 128LL, SS, nullptr);

    // 4. gates = [Mbuf | h_bf] @ W2bf^T + bias2, fused GRU epilogue
    //    (LDS-gather, BK=64 double-buffered) -> hnew bf16 directly
    gemm_dbuf<2, 3><<<dim3(256, 4, 1), 256, 0, stream>>>(
        Mbuf, h_bf, 256, HH, 256, 0, 0,
        W2bf, 384, 0, 0, bias2,
        hnew_bf, HH, 0, 0, 384, h_bf);

    // 5+6. fused q12-GEMM + attention tail v4 (2 blocks/batch, 1024 threads)
    k_tail<<<dim3(BB, 2), 1024, 0, stream>>>(hnew_bf, mask, Wq12, biasq12,
                                             W_q0, b_q0, out);
}